// Round 1
// baseline (92393.408 us; speedup 1.0000x reference)
//
#include <hip/hip_runtime.h>
#include <math.h>

#define BATCH 8192
#define KB 2048      // num basis
#define DD 1024      // dim basis (32*32)
#define LAM 0.1f
#define N_ITER 100
#define N_POWER 50

#define BM 128
#define BN 128
#define BKK 16

// ---------------- init ----------------
__global__ void k_init_zero(float* __restrict__ a0, float* __restrict__ y) {
  int n = BATCH * KB;
  for (int i = blockIdx.x * blockDim.x + threadIdx.x; i < n; i += gridDim.x * blockDim.x) {
    a0[i] = 0.f;
    y[i] = 0.f;
  }
}

__global__ void k_init_v(float* __restrict__ v) {
  int i = blockIdx.x * blockDim.x + threadIdx.x;
  if (i < KB) v[i] = 1.f;
}

// ---------------- power iteration ----------------
// MODE 0: w = G@v, partial[b] = block-sum of w_i^2   (for ||w||)
// MODE 1: w = G@v, partial[b] = block-sum of v_i*w_i (Rayleigh quotient numerator)
template <int MODE>
__global__ __launch_bounds__(256) void k_power_matvec(const float* __restrict__ G,
                                                      const float* __restrict__ vin,
                                                      float* __restrict__ wout,
                                                      float* __restrict__ partial) {
  int row = blockIdx.x * 256 + threadIdx.x;  // grid = KB/256 = 8 blocks
  const float* g = G + (size_t)row * KB;
  float s = 0.f;
#pragma unroll 4
  for (int j = 0; j < KB; j += 4) {
    float4 gg = *(const float4*)(g + j);
    float4 vv = *(const float4*)(vin + j);
    s = fmaf(gg.x, vv.x, s);
    s = fmaf(gg.y, vv.y, s);
    s = fmaf(gg.z, vv.z, s);
    s = fmaf(gg.w, vv.w, s);
  }
  wout[row] = s;
  float val = MODE ? vin[row] * s : s * s;
#pragma unroll
  for (int off = 32; off > 0; off >>= 1) val += __shfl_down(val, off, 64);
  __shared__ float red[4];
  int lane = threadIdx.x & 63, wid = threadIdx.x >> 6;
  if (lane == 0) red[wid] = val;
  __syncthreads();
  if (threadIdx.x == 0) partial[blockIdx.x] = red[0] + red[1] + red[2] + red[3];
}

__global__ void k_power_scale(const float* __restrict__ w, float* __restrict__ v,
                              const float* __restrict__ partial) {
  float n2 = 0.f;
#pragma unroll
  for (int i = 0; i < 8; ++i) n2 += partial[i];
  int i = blockIdx.x * 256 + threadIdx.x;  // 8 blocks x 256 = 2048
  v[i] = w[i] / sqrtf(n2);
}

__global__ void k_compute_step(const float* __restrict__ partialL, float* __restrict__ stepbuf) {
  float L = 0.f;
#pragma unroll
  for (int i = 0; i < 8; ++i) L += partialL[i];
  stepbuf[0] = 1.f / L;  // step; thr = LAM*step derived in epilogue
}

// ---------------- GEMM NN: C[m,n] = sum_k A[m,k]*Bm[k,n] ----------------
// EPI 0: C = acc            (recon)
// EPI 1: C = acc - X        (residual)
template <int EPI>
__global__ __launch_bounds__(256) void k_gemm_nn(const float* __restrict__ A,
                                                 const float* __restrict__ Bm,
                                                 float* __restrict__ C,
                                                 const float* __restrict__ X,
                                                 int M, int N, int Kd) {
  __shared__ float As[BKK][BM + 4];
  __shared__ float Bs[BKK][BN + 4];
  int tx = threadIdx.x & 15, ty = threadIdx.x >> 4;
  int row0 = blockIdx.y * BM, col0 = blockIdx.x * BN;
  float acc[8][8] = {};

  for (int k0 = 0; k0 < Kd; k0 += BKK) {
#pragma unroll
    for (int i = 0; i < 2; ++i) {
      int f = threadIdx.x + 256 * i;
      int r = f >> 2, kk = (f & 3) << 2;
      float4 a = *(const float4*)&A[(row0 + r) * Kd + k0 + kk];
      As[kk + 0][r] = a.x;
      As[kk + 1][r] = a.y;
      As[kk + 2][r] = a.z;
      As[kk + 3][r] = a.w;
    }
#pragma unroll
    for (int i = 0; i < 2; ++i) {
      int f = threadIdx.x + 256 * i;
      int kr = f >> 5, nc = (f & 31) << 2;
      *(float4*)&Bs[kr][nc] = *(const float4*)&Bm[(k0 + kr) * N + col0 + nc];
    }
    __syncthreads();
#pragma unroll
    for (int k = 0; k < BKK; ++k) {
      float a[8], b[8];
      *(float4*)&a[0] = *(const float4*)&As[k][ty * 8];
      *(float4*)&a[4] = *(const float4*)&As[k][ty * 8 + 4];
      *(float4*)&b[0] = *(const float4*)&Bs[k][tx * 8];
      *(float4*)&b[4] = *(const float4*)&Bs[k][tx * 8 + 4];
#pragma unroll
      for (int i = 0; i < 8; ++i)
#pragma unroll
        for (int j = 0; j < 8; ++j) acc[i][j] = fmaf(a[i], b[j], acc[i][j]);
    }
    __syncthreads();
  }

  int m0 = row0 + ty * 8, n0 = col0 + tx * 8;
#pragma unroll
  for (int i = 0; i < 8; ++i) {
    int m = m0 + i;
#pragma unroll
    for (int j4 = 0; j4 < 2; ++j4) {
      int n = n0 + j4 * 4;
      float4 c;
      c.x = acc[i][j4 * 4 + 0];
      c.y = acc[i][j4 * 4 + 1];
      c.z = acc[i][j4 * 4 + 2];
      c.w = acc[i][j4 * 4 + 3];
      if (EPI == 1) {
        float4 xv = *(const float4*)&X[m * N + n];
        c.x -= xv.x; c.y -= xv.y; c.z -= xv.z; c.w -= xv.w;
      }
      *(float4*)&C[m * N + n] = c;
    }
  }
}

// ---------------- GEMM NT: C[m,n] = sum_d A[m,d]*Bt[n,d] ----------------
// EPI 0: C = acc (Gram)
// EPI 2: FISTA update fused: g=acc; z=y-step*g; a=soft(z,thr);
//        y_new = a + mu*(a - a_prev); writes Acur and Yio (in place).
template <int EPI>
__global__ __launch_bounds__(256) void k_gemm_nt(const float* __restrict__ A,
                                                 const float* __restrict__ Bt,
                                                 float* __restrict__ C,
                                                 float* __restrict__ Yio,
                                                 const float* __restrict__ Aprev,
                                                 float* __restrict__ Acur,
                                                 const float* __restrict__ stepbuf,
                                                 float mu, int M, int N, int Kd) {
  __shared__ float As[BKK][BM + 4];
  __shared__ float Bs[BKK][BN + 4];
  int tx = threadIdx.x & 15, ty = threadIdx.x >> 4;
  int row0 = blockIdx.y * BM, col0 = blockIdx.x * BN;
  float acc[8][8] = {};

  for (int k0 = 0; k0 < Kd; k0 += BKK) {
#pragma unroll
    for (int i = 0; i < 2; ++i) {
      int f = threadIdx.x + 256 * i;
      int r = f >> 2, kk = (f & 3) << 2;
      float4 a = *(const float4*)&A[(row0 + r) * Kd + k0 + kk];
      As[kk + 0][r] = a.x;
      As[kk + 1][r] = a.y;
      As[kk + 2][r] = a.z;
      As[kk + 3][r] = a.w;
    }
#pragma unroll
    for (int i = 0; i < 2; ++i) {
      int f = threadIdx.x + 256 * i;
      int nr = f >> 2, dd = (f & 3) << 2;
      float4 b = *(const float4*)&Bt[(col0 + nr) * Kd + k0 + dd];
      Bs[dd + 0][nr] = b.x;
      Bs[dd + 1][nr] = b.y;
      Bs[dd + 2][nr] = b.z;
      Bs[dd + 3][nr] = b.w;
    }
    __syncthreads();
#pragma unroll
    for (int k = 0; k < BKK; ++k) {
      float a[8], b[8];
      *(float4*)&a[0] = *(const float4*)&As[k][ty * 8];
      *(float4*)&a[4] = *(const float4*)&As[k][ty * 8 + 4];
      *(float4*)&b[0] = *(const float4*)&Bs[k][tx * 8];
      *(float4*)&b[4] = *(const float4*)&Bs[k][tx * 8 + 4];
#pragma unroll
      for (int i = 0; i < 8; ++i)
#pragma unroll
        for (int j = 0; j < 8; ++j) acc[i][j] = fmaf(a[i], b[j], acc[i][j]);
    }
    __syncthreads();
  }

  int m0 = row0 + ty * 8, n0 = col0 + tx * 8;
  if (EPI == 0) {
#pragma unroll
    for (int i = 0; i < 8; ++i) {
      int m = m0 + i;
#pragma unroll
      for (int j4 = 0; j4 < 2; ++j4) {
        int n = n0 + j4 * 4;
        float4 c;
        c.x = acc[i][j4 * 4 + 0];
        c.y = acc[i][j4 * 4 + 1];
        c.z = acc[i][j4 * 4 + 2];
        c.w = acc[i][j4 * 4 + 3];
        *(float4*)&C[m * N + n] = c;
      }
    }
  } else {
    const float step = stepbuf[0];
    const float thr = LAM * step;
#pragma unroll
    for (int i = 0; i < 8; ++i) {
      int m = m0 + i;
#pragma unroll
      for (int j4 = 0; j4 < 2; ++j4) {
        int n = n0 + j4 * 4;
        float4 yv = *(const float4*)&Yio[m * N + n];
        float4 ap = *(const float4*)&Aprev[m * N + n];
        float4 av, yn;
        {
          float z = yv.x - step * acc[i][j4 * 4 + 0];
          float s = fabsf(z) - thr;
          av.x = s > 0.f ? copysignf(s, z) : 0.f;
          yn.x = av.x + mu * (av.x - ap.x);
        }
        {
          float z = yv.y - step * acc[i][j4 * 4 + 1];
          float s = fabsf(z) - thr;
          av.y = s > 0.f ? copysignf(s, z) : 0.f;
          yn.y = av.y + mu * (av.y - ap.y);
        }
        {
          float z = yv.z - step * acc[i][j4 * 4 + 2];
          float s = fabsf(z) - thr;
          av.z = s > 0.f ? copysignf(s, z) : 0.f;
          yn.z = av.z + mu * (av.z - ap.z);
        }
        {
          float z = yv.w - step * acc[i][j4 * 4 + 3];
          float s = fabsf(z) - thr;
          av.w = s > 0.f ? copysignf(s, z) : 0.f;
          yn.w = av.w + mu * (av.w - ap.w);
        }
        *(float4*)&Acur[m * N + n] = av;
        *(float4*)&Yio[m * N + n] = yn;
      }
    }
  }
}

// ---------------- launch ----------------
extern "C" void kernel_launch(void* const* d_in, const int* in_sizes, int n_in,
                              void* d_out, int out_size, void* d_ws, size_t ws_size,
                              hipStream_t stream) {
  const float* x = (const float*)d_in[0];    // [8192,32,32] -> [8192,1024]
  const float* phi = (const float*)d_in[1];  // [2048,1024]
  float* out = (float*)d_out;
  float* alpha_out = out;                   // [8192*2048] — used as A0 (alpha ping-pong)
  float* recon_out = out + (size_t)BATCH * KB;  // [8192*1024] — used as resid scratch

  float* ws = (float*)d_ws;
  float* G = ws;                         // KB*KB       = 4,194,304
  float* Y = G + (size_t)KB * KB;        // BATCH*KB    = 16,777,216
  float* A1 = Y + (size_t)BATCH * KB;    // BATCH*KB    = 16,777,216
  float* vbuf = A1 + (size_t)BATCH * KB; // KB
  float* wbuf = vbuf + KB;               // KB
  float* scal = wbuf + KB;               // 512: [s*8] norm partials (s<50), [400..407] L partials, [408] step

  const size_t need = ((size_t)KB * KB + 2ull * BATCH * KB + 2 * KB + 512) * sizeof(float);
  if (ws_size < need) return;  // cannot proceed without scratch

  // alpha0 = 0, y0 = 0
  k_init_zero<<<2048, 256, 0, stream>>>(alpha_out, Y);
  k_init_v<<<8, 256, 0, stream>>>(vbuf);

  // G = phi @ phi^T
  k_gemm_nt<0><<<dim3(KB / BN, KB / BM), 256, 0, stream>>>(
      phi, phi, G, nullptr, nullptr, nullptr, nullptr, 0.f, KB, KB, DD);

  // power iteration: v_{s+1} = (G v_s) / ||G v_s||
  for (int s = 0; s < N_POWER; ++s) {
    k_power_matvec<0><<<KB / 256, 256, 0, stream>>>(G, vbuf, wbuf, scal + s * 8);
    k_power_scale<<<KB / 256, 256, 0, stream>>>(wbuf, vbuf, scal + s * 8);
  }
  // L = v @ (G @ v); step = 1/L
  k_power_matvec<1><<<KB / 256, 256, 0, stream>>>(G, vbuf, wbuf, scal + 400);
  k_compute_step<<<1, 1, 0, stream>>>(scal + 400, scal + 408);

  // FISTA
  float t = 1.f;
  float* Ap = alpha_out;  // alpha_prev (zeros)
  float* Ac = A1;
  float* Rbuf = recon_out;  // resid scratch lives in the recon output region
  for (int it = 0; it < N_ITER; ++it) {
    // resid = y @ phi - x   [BATCH, DD]
    k_gemm_nn<1><<<dim3(DD / BN, BATCH / BM), 256, 0, stream>>>(
        Y, phi, Rbuf, x, BATCH, DD, KB);
    float tn = 0.5f * (1.f + sqrtf(1.f + 4.f * t * t));
    float mu = (t - 1.f) / tn;
    // grad = resid @ phi^T; alpha = soft(y - step*grad); y = alpha + mu*(alpha - alpha_prev)
    k_gemm_nt<2><<<dim3(KB / BN, BATCH / BM), 256, 0, stream>>>(
        Rbuf, phi, nullptr, Y, Ap, Ac, scal + 408, mu, BATCH, KB, DD);
    t = tn;
    float* tmp = Ap; Ap = Ac; Ac = tmp;
  }
  // After 100 iterations (even), final alpha is in alpha_out (== Ap).

  // recon = alpha @ phi  [BATCH, DD]
  k_gemm_nn<0><<<dim3(DD / BN, BATCH / BM), 256, 0, stream>>>(
      Ap, phi, recon_out, nullptr, BATCH, DD, KB);
}

// Round 3
// 30300.806 us; speedup vs baseline: 3.0492x; 3.0492x over previous
//
#include <hip/hip_runtime.h>
#include <math.h>

#define BATCH 8192
#define KB 2048      // num basis
#define DD 1024      // dim basis (32*32)
#define LAM 0.1f
#define N_ITER 100
#define N_POWER 50

typedef unsigned short u16;
using short8 = __attribute__((ext_vector_type(8))) short;
using f32x4  = __attribute__((ext_vector_type(4))) float;

// ---------- bf16 split helpers (bit ops; RNE) ----------
__device__ __forceinline__ u16 f2bf(float f) {
  unsigned int u = __builtin_bit_cast(unsigned int, f);
  u = u + 0x7FFFu + ((u >> 16) & 1u);
  return (u16)(u >> 16);
}
__device__ __forceinline__ float bf2f(u16 s) {
  unsigned int u = ((unsigned int)s) << 16;
  return __builtin_bit_cast(float, u);
}

// ---------------- init ----------------
__global__ void k_init_zero(float* __restrict__ a0, u16* __restrict__ yh, u16* __restrict__ yl) {
  int n = BATCH * KB;
  for (int i = blockIdx.x * blockDim.x + threadIdx.x; i < n; i += gridDim.x * blockDim.x) {
    a0[i] = 0.f;
    yh[i] = 0;
    yl[i] = 0;
  }
}

__global__ void k_init_v(float* __restrict__ v) {
  int i = blockIdx.x * blockDim.x + threadIdx.x;
  if (i < KB) v[i] = 1.f;
}

// ---------------- phi splitting ----------------
__global__ void k_split_phi(const float* __restrict__ phi, u16* __restrict__ h, u16* __restrict__ lo) {
  int i = blockIdx.x * 256 + threadIdx.x;  // grid = KB*DD/256
  float v = phi[i];
  u16 hh = f2bf(v);
  h[i] = hh;
  lo[i] = f2bf(v - bf2f(hh));
}

__global__ __launch_bounds__(256) void k_split_phiT(const float* __restrict__ phi,
                                                    u16* __restrict__ th, u16* __restrict__ tl) {
  __shared__ float t[32][33];
  int k0 = blockIdx.y * 32, d0 = blockIdx.x * 32;
  int tx = threadIdx.x & 31, ty = threadIdx.x >> 5;  // 8 rows per pass
#pragma unroll
  for (int rr = 0; rr < 32; rr += 8)
    t[ty + rr][tx] = phi[(size_t)(k0 + ty + rr) * DD + d0 + tx];
  __syncthreads();
#pragma unroll
  for (int rr = 0; rr < 32; rr += 8) {
    float v = t[tx][ty + rr];  // = phi[k0+tx][d0+ty+rr]
    u16 hh = f2bf(v);
    size_t idx = (size_t)(d0 + ty + rr) * KB + (k0 + tx);
    th[idx] = hh;
    tl[idx] = f2bf(v - bf2f(hh));
  }
}

// ---------------- power iteration ----------------
// 64 blocks x 256 thr; 8 threads per row (seg over K).
// MODE 0: w=G@v, partial[b]=sum w^2 ; MODE 1: partial[b]=sum v*w
template <int MODE>
__global__ __launch_bounds__(256) void k_power_matvec(const float* __restrict__ G,
                                                      const float* __restrict__ vin,
                                                      float* __restrict__ wout,
                                                      float* __restrict__ partial) {
  int rloc = threadIdx.x >> 3;       // 32 rows per block
  int seg = threadIdx.x & 7;         // 8 segments of 256
  int row = blockIdx.x * 32 + rloc;
  const float* g = G + (size_t)row * KB + seg * 256;
  const float* vv = vin + seg * 256;
  float s = 0.f;
#pragma unroll 8
  for (int j = 0; j < 256; j += 4) {
    float4 gg = *(const float4*)(g + j);
    float4 vx = *(const float4*)(vv + j);
    s = fmaf(gg.x, vx.x, fmaf(gg.y, vx.y, fmaf(gg.z, vx.z, fmaf(gg.w, vx.w, s))));
  }
  // reduce segments (low 3 lane bits): all lanes end with the row sum
#pragma unroll
  for (int off = 1; off < 8; off <<= 1) s += __shfl_xor(s, off, 64);
  if (seg == 0) wout[row] = s;
  float val = (seg == 0) ? (MODE ? vin[row] * s : s * s) : 0.f;
#pragma unroll
  for (int off = 8; off < 64; off <<= 1) val += __shfl_xor(val, off, 64);
  __shared__ float red[4];
  int lane = threadIdx.x & 63, wid = threadIdx.x >> 6;
  if (lane == 0) red[wid] = val;
  __syncthreads();
  if (threadIdx.x == 0) partial[blockIdx.x] = red[0] + red[1] + red[2] + red[3];
}

__global__ void k_power_scale(const float* __restrict__ w, float* __restrict__ v,
                              const float* __restrict__ partial) {
  float n2 = 0.f;
#pragma unroll
  for (int i = 0; i < 64; ++i) n2 += partial[i];
  int i = blockIdx.x * 256 + threadIdx.x;  // 8 blocks x 256 = 2048
  v[i] = w[i] / sqrtf(n2);
}

__global__ void k_compute_step(const float* __restrict__ partialL, float* __restrict__ stepbuf) {
  float L = 0.f;
#pragma unroll
  for (int i = 0; i < 64; ++i) L += partialL[i];
  stepbuf[0] = 1.f / L;
}

// ---------------- split-bf16 MFMA GEMM ----------------
// C[m,n] = sum_k A[m,k]*B[n,k]  (both operands [row][k], k contiguous, bf16 hi/lo)
// EPI 0: resid epilogue: v = acc - X[m,n]; write outH/outL (bf16 split of v)
// EPI 1: FISTA epilogue: g = acc; y = Yh+Yl; z = y - step*g; a = soft(z, lam*step);
//        yn = a + mu*(a - Aprev); Acur = a; Yh/Yl = split(yn)
template <int EPI>
__global__ __launch_bounds__(256) void k_gemm_mfma(
    const u16* __restrict__ Ah, const u16* __restrict__ Al,
    const u16* __restrict__ Bh, const u16* __restrict__ Bl,
    int N, int K,
    const float* __restrict__ X,
    u16* __restrict__ outH, u16* __restrict__ outL,
    u16* __restrict__ Yh, u16* __restrict__ Yl,
    const float* __restrict__ Aprev, float* __restrict__ Acur,
    const float* __restrict__ stepbuf, float mu) {
  __shared__ u16 lds[4 * 128 * 32];
  u16* sAh = lds;
  u16* sAl = lds + 4096;
  u16* sBh = lds + 8192;
  u16* sBl = lds + 12288;

  const int tid = threadIdx.x;
  const int w = tid >> 6, l = tid & 63;
  const int row0 = blockIdx.y * 128, col0 = blockIdx.x * 128;
  const int wm = (w >> 1) * 64, wn = (w & 1) * 64;
  const int lrow = l & 15, lk = (l >> 4) * 8;

  f32x4 zero4 = {0.f, 0.f, 0.f, 0.f};
  f32x4 acc[4][4];
#pragma unroll
  for (int i = 0; i < 4; ++i)
#pragma unroll
    for (int j = 0; j < 4; ++j) acc[i][j] = zero4;

  for (int k0 = 0; k0 < K; k0 += 32) {
    // ---- stage 4 streams: each wave 2 x global_load_lds(16B) per stream ----
    {
      const u16* gs[4] = {Ah, Al, Bh, Bl};
      const int r0s[4] = {row0, row0, col0, col0};
#pragma unroll
      for (int st = 0; st < 4; ++st) {
        u16* s = lds + st * 4096;
#pragma unroll
        for (int h = 0; h < 2; ++h) {
          int ch = h * 256 + w * 64 + l;                 // 16B chunk index in tile
          const u16* gp = gs[st] + (size_t)(r0s[st] + (ch >> 2)) * K + k0 + (ch & 3) * 8;
          u16* sp = s + (h * 256 + w * 64) * 8;          // wave-uniform base
          __builtin_amdgcn_global_load_lds((const __attribute__((address_space(1))) void*)gp,
                                           (__attribute__((address_space(3))) void*)sp, 16, 0, 0);
        }
      }
    }
    __syncthreads();

    short8 ah[4], al[4];
#pragma unroll
    for (int i = 0; i < 4; ++i) {
      int r = wm + i * 16 + lrow;
      ah[i] = *(const short8*)&sAh[r * 32 + lk];
      al[i] = *(const short8*)&sAl[r * 32 + lk];
    }
#pragma unroll
    for (int j = 0; j < 4; ++j) {
      int r = wn + j * 16 + lrow;
      short8 bh = *(const short8*)&sBh[r * 32 + lk];
      short8 bl = *(const short8*)&sBl[r * 32 + lk];
#pragma unroll
      for (int i = 0; i < 4; ++i) {
        acc[i][j] = __builtin_amdgcn_mfma_f32_16x16x32_bf16(ah[i], bh, acc[i][j], 0, 0, 0);
        acc[i][j] = __builtin_amdgcn_mfma_f32_16x16x32_bf16(ah[i], bl, acc[i][j], 0, 0, 0);
        acc[i][j] = __builtin_amdgcn_mfma_f32_16x16x32_bf16(al[i], bh, acc[i][j], 0, 0, 0);
      }
    }
    __syncthreads();
  }

  // ---- epilogue ----
  if (EPI == 0) {
#pragma unroll
    for (int i = 0; i < 4; ++i) {
#pragma unroll
      for (int r = 0; r < 4; ++r) {
        int m = row0 + wm + i * 16 + ((l >> 4) << 2) + r;
        size_t base = (size_t)m * N;
#pragma unroll
        for (int j = 0; j < 4; ++j) {
          int n = col0 + wn + j * 16 + (l & 15);
          float v = acc[i][j][r] - X[base + n];
          u16 hh = f2bf(v);
          outH[base + n] = hh;
          outL[base + n] = f2bf(v - bf2f(hh));
        }
      }
    }
  } else {
    const float step = stepbuf[0];
    const float thr = LAM * step;
#pragma unroll
    for (int i = 0; i < 4; ++i) {
#pragma unroll
      for (int r = 0; r < 4; ++r) {
        int m = row0 + wm + i * 16 + ((l >> 4) << 2) + r;
        size_t base = (size_t)m * N;
#pragma unroll
        for (int j = 0; j < 4; ++j) {
          int n = col0 + wn + j * 16 + (l & 15);
          size_t idx = base + n;
          float g = acc[i][j][r];
          float y = bf2f(Yh[idx]) + bf2f(Yl[idx]);
          float z = y - step * g;
          float az = fabsf(z) - thr;
          float a = az > 0.f ? copysignf(az, z) : 0.f;
          float yn = a + mu * (a - Aprev[idx]);
          Acur[idx] = a;
          u16 hh = f2bf(yn);
          Yh[idx] = hh;
          Yl[idx] = f2bf(yn - bf2f(hh));
        }
      }
    }
  }
}

// ---------------- fp32 GEMMs (one-time: Gram, recon) ----------------
#define BM 128
#define BN 128
#define BKK 16

// Gram: C[m,n] = sum_d A[m,d]*B[n,d]   (NT)
__global__ __launch_bounds__(256) void k_gram_f32(const float* __restrict__ A,
                                                  const float* __restrict__ Bt,
                                                  float* __restrict__ C, int M, int N, int Kd) {
  __shared__ float As[BKK][BM + 4];
  __shared__ float Bs[BKK][BN + 4];
  int tx = threadIdx.x & 15, ty = threadIdx.x >> 4;
  int row0 = blockIdx.y * BM, col0 = blockIdx.x * BN;
  float acc[8][8] = {};
  for (int k0 = 0; k0 < Kd; k0 += BKK) {
#pragma unroll
    for (int i = 0; i < 2; ++i) {
      int f = threadIdx.x + 256 * i;
      int r = f >> 2, kk = (f & 3) << 2;
      float4 a = *(const float4*)&A[(size_t)(row0 + r) * Kd + k0 + kk];
      As[kk + 0][r] = a.x; As[kk + 1][r] = a.y; As[kk + 2][r] = a.z; As[kk + 3][r] = a.w;
      float4 b = *(const float4*)&Bt[(size_t)(col0 + r) * Kd + k0 + kk];
      Bs[kk + 0][r] = b.x; Bs[kk + 1][r] = b.y; Bs[kk + 2][r] = b.z; Bs[kk + 3][r] = b.w;
    }
    __syncthreads();
#pragma unroll
    for (int k = 0; k < BKK; ++k) {
      float a[8], b[8];
      *(float4*)&a[0] = *(const float4*)&As[k][ty * 8];
      *(float4*)&a[4] = *(const float4*)&As[k][ty * 8 + 4];
      *(float4*)&b[0] = *(const float4*)&Bs[k][tx * 8];
      *(float4*)&b[4] = *(const float4*)&Bs[k][tx * 8 + 4];
#pragma unroll
      for (int i = 0; i < 8; ++i)
#pragma unroll
        for (int j = 0; j < 8; ++j) acc[i][j] = fmaf(a[i], b[j], acc[i][j]);
    }
    __syncthreads();
  }
  int m0 = row0 + ty * 8, n0 = col0 + tx * 8;
#pragma unroll
  for (int i = 0; i < 8; ++i)
#pragma unroll
    for (int j4 = 0; j4 < 2; ++j4) {
      float4 c;
      c.x = acc[i][j4 * 4 + 0]; c.y = acc[i][j4 * 4 + 1];
      c.z = acc[i][j4 * 4 + 2]; c.w = acc[i][j4 * 4 + 3];
      *(float4*)&C[(size_t)(m0 + i) * N + n0 + j4 * 4] = c;
    }
}

// Recon: C[m,n] = sum_k A[m,k]*Bm[k,n]  (NN)
__global__ __launch_bounds__(256) void k_recon_f32(const float* __restrict__ A,
                                                   const float* __restrict__ Bm,
                                                   float* __restrict__ C, int M, int N, int Kd) {
  __shared__ float As[BKK][BM + 4];
  __shared__ float Bs[BKK][BN + 4];
  int tx = threadIdx.x & 15, ty = threadIdx.x >> 4;
  int row0 = blockIdx.y * BM, col0 = blockIdx.x * BN;
  float acc[8][8] = {};
  for (int k0 = 0; k0 < Kd; k0 += BKK) {
#pragma unroll
    for (int i = 0; i < 2; ++i) {
      int f = threadIdx.x + 256 * i;
      int r = f >> 2, kk = (f & 3) << 2;
      float4 a = *(const float4*)&A[(size_t)(row0 + r) * Kd + k0 + kk];
      As[kk + 0][r] = a.x; As[kk + 1][r] = a.y; As[kk + 2][r] = a.z; As[kk + 3][r] = a.w;
      int kr = f >> 5, nc = (f & 31) << 2;
      *(float4*)&Bs[kr][nc] = *(const float4*)&Bm[(size_t)(k0 + kr) * N + col0 + nc];
    }
    __syncthreads();
#pragma unroll
    for (int k = 0; k < BKK; ++k) {
      float a[8], b[8];
      *(float4*)&a[0] = *(const float4*)&As[k][ty * 8];
      *(float4*)&a[4] = *(const float4*)&As[k][ty * 8 + 4];
      *(float4*)&b[0] = *(const float4*)&Bs[k][tx * 8];
      *(float4*)&b[4] = *(const float4*)&Bs[k][tx * 8 + 4];
#pragma unroll
      for (int i = 0; i < 8; ++i)
#pragma unroll
        for (int j = 0; j < 8; ++j) acc[i][j] = fmaf(a[i], b[j], acc[i][j]);
    }
    __syncthreads();
  }
  int m0 = row0 + ty * 8, n0 = col0 + tx * 8;
#pragma unroll
  for (int i = 0; i < 8; ++i)
#pragma unroll
    for (int j4 = 0; j4 < 2; ++j4) {
      float4 c;
      c.x = acc[i][j4 * 4 + 0]; c.y = acc[i][j4 * 4 + 1];
      c.z = acc[i][j4 * 4 + 2]; c.w = acc[i][j4 * 4 + 3];
      *(float4*)&C[(size_t)(m0 + i) * N + n0 + j4 * 4] = c;
    }
}

// ---------------- launch ----------------
extern "C" void kernel_launch(void* const* d_in, const int* in_sizes, int n_in,
                              void* d_out, int out_size, void* d_ws, size_t ws_size,
                              hipStream_t stream) {
  const float* x = (const float*)d_in[0];    // [8192,1024]
  const float* phi = (const float*)d_in[1];  // [2048,1024]
  float* out = (float*)d_out;
  float* alpha_out = out;                          // [BATCH*KB] — alpha ping-pong A0
  float* recon_out = out + (size_t)BATCH * KB;     // [BATCH*DD] floats (33.55 MB)

  // ---- workspace: only buffers that must live through the FISTA loop ----
  float* ws = (float*)d_ws;
  float* A1 = ws;                             // BATCH*KB floats (67.1 MB)
  u16* Yh = (u16*)(A1 + (size_t)BATCH * KB);  // BATCH*KB u16
  u16* Yl = Yh + (size_t)BATCH * KB;          // BATCH*KB u16
  u16* phiH = Yl + (size_t)BATCH * KB;        // KB*DD u16
  u16* phiL = phiH + (size_t)KB * DD;
  u16* phiTH = phiL + (size_t)KB * DD;        // DD*KB u16
  u16* phiTL = phiTH + (size_t)KB * DD;
  float* stepbuf = (float*)(phiTL + (size_t)KB * DD);  // 1 float (+pad)

  const size_t need = (size_t)BATCH * KB * 4 +                 // A1
                      ((size_t)2 * BATCH * KB + 4ull * KB * DD) * 2 +  // Yh,Yl,phi splits
                      64;                                       // stepbuf
  if (ws_size < need) return;  // ~151.0 MB, <= proven round-1 floor

  // ---- pre-FISTA temporaries live in the recon region of d_out ----
  // All are dead before the first FISTA iteration overwrites this region
  // with resid scratch (residH/residL fill it exactly).
  float* G = recon_out;                        // KB*KB floats (16.78 MB)
  float* vbuf = G + (size_t)KB * KB;           // KB
  float* wbuf = vbuf + KB;                     // KB
  float* normPart = wbuf + KB;                 // 50*64 floats
  float* LPart = normPart + 3200;              // 64 floats
  // total: 4,201,664 floats < 8,388,608 available

  u16* residH = (u16*)recon_out;               // BATCH*DD u16
  u16* residL = residH + (size_t)BATCH * DD;   // BATCH*DD u16

  // init: alpha0 = 0, y0 = 0 (hi/lo), v = 1
  k_init_zero<<<2048, 256, 0, stream>>>(alpha_out, Yh, Yl);
  k_init_v<<<8, 256, 0, stream>>>(vbuf);

  // phi splits (both layouts)
  k_split_phi<<<(KB * DD) / 256, 256, 0, stream>>>(phi, phiH, phiL);
  k_split_phiT<<<dim3(DD / 32, KB / 32), 256, 0, stream>>>(phi, phiTH, phiTL);

  // G = phi @ phi^T (fp32)
  k_gram_f32<<<dim3(KB / BN, KB / BM), 256, 0, stream>>>(phi, phi, G, KB, KB, DD);

  // power iteration
  for (int s = 0; s < N_POWER; ++s) {
    k_power_matvec<0><<<64, 256, 0, stream>>>(G, vbuf, wbuf, normPart + s * 64);
    k_power_scale<<<KB / 256, 256, 0, stream>>>(wbuf, vbuf, normPart + s * 64);
  }
  k_power_matvec<1><<<64, 256, 0, stream>>>(G, vbuf, wbuf, LPart);
  k_compute_step<<<1, 1, 0, stream>>>(LPart, stepbuf);

  // FISTA
  float t = 1.f;
  float* Ap = alpha_out;
  float* Ac = A1;
  for (int it = 0; it < N_ITER; ++it) {
    // resid(split) = Y @ phi - x : A=[Yh,Yl] (K=KB), B=phiT (rows=DD, K=KB)
    k_gemm_mfma<0><<<dim3(DD / 128, BATCH / 128), 256, 0, stream>>>(
        Yh, Yl, phiTH, phiTL, DD, KB, x, residH, residL,
        nullptr, nullptr, nullptr, nullptr, nullptr, 0.f);
    float tn = 0.5f * (1.f + sqrtf(1.f + 4.f * t * t));
    float mu = (t - 1.f) / tn;
    // grad = resid @ phi^T + fused FISTA update : A=[residH,residL] (K=DD), B=phi (rows=KB, K=DD)
    k_gemm_mfma<1><<<dim3(KB / 128, BATCH / 128), 256, 0, stream>>>(
        residH, residL, phiH, phiL, KB, DD, nullptr, nullptr, nullptr,
        Yh, Yl, Ap, Ac, stepbuf, mu);
    t = tn;
    float* tmp = Ap; Ap = Ac; Ac = tmp;
  }
  // N_ITER=100 (even): final alpha is in alpha_out (== Ap)

  // recon = alpha @ phi (fp32, overwrites resid scratch)
  k_recon_f32<<<dim3(DD / BN, BATCH / BM), 256, 0, stream>>>(
      Ap, phi, recon_out, BATCH, DD, KB);
}

// Round 5
// 29010.922 us; speedup vs baseline: 3.1848x; 1.0445x over previous
//
#include <hip/hip_runtime.h>
#include <hip/hip_cooperative_groups.h>
#include <math.h>

namespace cg = cooperative_groups;

#define BATCH 8192
#define KB 2048      // num basis (N of fused GEMM)
#define DD 1024      // dim basis
#define LAM 0.1f
#define N_ITER 100
#define N_POWER 50
#define NTILES 96    // K' = 6144 = 96 * 64

typedef unsigned short u16;
using short8 = __attribute__((ext_vector_type(8))) short;
using f32x4  = __attribute__((ext_vector_type(4))) float;

// ---------- bf16 split helpers (RNE) ----------
__device__ __forceinline__ u16 f2bf(float f) {
  unsigned int u = __builtin_bit_cast(unsigned int, f);
  u = u + 0x7FFFu + ((u >> 16) & 1u);
  return (u16)(u >> 16);
}
__device__ __forceinline__ float bf2f(u16 s) {
  unsigned int u = ((unsigned int)s) << 16;
  return __builtin_bit_cast(float, u);
}

// ---------------- utility kernels ----------------
__global__ void k_split_f32(const float* __restrict__ in, u16* __restrict__ h,
                            u16* __restrict__ lo, int n) {
  for (int i = blockIdx.x * blockDim.x + threadIdx.x; i < n; i += gridDim.x * blockDim.x) {
    float v = in[i];
    u16 hh = f2bf(v);
    h[i] = hh;
    lo[i] = f2bf(v - bf2f(hh));
  }
}

__global__ void k_zero2(float4* __restrict__ a, int na, float4* __restrict__ b, int nb) {
  float4 z = {0.f, 0.f, 0.f, 0.f};
  for (int i = blockIdx.x * blockDim.x + threadIdx.x; i < na; i += gridDim.x * blockDim.x)
    a[i] = z;
  for (int i = blockIdx.x * blockDim.x + threadIdx.x; i < nb; i += gridDim.x * blockDim.x)
    b[i] = z;
}

__global__ void k_init_v(float* __restrict__ v) {
  int i = blockIdx.x * blockDim.x + threadIdx.x;
  if (i < KB) v[i] = 1.f;
}

// ---------------- power iteration (proven r3) ----------------
template <int MODE>
__global__ __launch_bounds__(256) void k_power_matvec(const float* __restrict__ G,
                                                      const float* __restrict__ vin,
                                                      float* __restrict__ wout,
                                                      float* __restrict__ partial) {
  int rloc = threadIdx.x >> 3;
  int seg = threadIdx.x & 7;
  int row = blockIdx.x * 32 + rloc;
  const float* g = G + (size_t)row * KB + seg * 256;
  const float* vv = vin + seg * 256;
  float s = 0.f;
#pragma unroll 8
  for (int j = 0; j < 256; j += 4) {
    float4 gg = *(const float4*)(g + j);
    float4 vx = *(const float4*)(vv + j);
    s = fmaf(gg.x, vx.x, fmaf(gg.y, vx.y, fmaf(gg.z, vx.z, fmaf(gg.w, vx.w, s))));
  }
#pragma unroll
  for (int off = 1; off < 8; off <<= 1) s += __shfl_xor(s, off, 64);
  if (seg == 0) wout[row] = s;
  float val = (seg == 0) ? (MODE ? vin[row] * s : s * s) : 0.f;
#pragma unroll
  for (int off = 8; off < 64; off <<= 1) val += __shfl_xor(val, off, 64);
  __shared__ float red[4];
  int lane = threadIdx.x & 63, wid = threadIdx.x >> 6;
  if (lane == 0) red[wid] = val;
  __syncthreads();
  if (threadIdx.x == 0) partial[blockIdx.x] = red[0] + red[1] + red[2] + red[3];
}

__global__ void k_power_scale(const float* __restrict__ w, float* __restrict__ v,
                              const float* __restrict__ partial) {
  float n2 = 0.f;
#pragma unroll
  for (int i = 0; i < 64; ++i) n2 += partial[i];
  int i = blockIdx.x * 256 + threadIdx.x;
  v[i] = w[i] / sqrtf(n2);
}

__global__ void k_compute_step(const float* __restrict__ partialL, float* __restrict__ stepbuf) {
  float L = 0.f;
#pragma unroll
  for (int i = 0; i < 64; ++i) L += partialL[i];
  stepbuf[0] = 1.f / L;
}

// ---------------- Cx = x @ phi^T (split-bf16 MFMA, fp32 out; r3-proven structure) ----------------
__global__ __launch_bounds__(256) void k_xphiT(
    const u16* __restrict__ Ah, const u16* __restrict__ Al,
    const u16* __restrict__ Bh, const u16* __restrict__ Bl,
    float* __restrict__ Cout, int N, int K) {
  __shared__ u16 lds[4 * 128 * 32];
  const int tid = threadIdx.x;
  const int w = tid >> 6, l = tid & 63;
  const int row0 = blockIdx.y * 128, col0 = blockIdx.x * 128;
  const int wm = (w >> 1) * 64, wn = (w & 1) * 64;
  const int lrow = l & 15, lk = (l >> 4) * 8;

  f32x4 zero4 = {0.f, 0.f, 0.f, 0.f};
  f32x4 acc[4][4];
#pragma unroll
  for (int i = 0; i < 4; ++i)
#pragma unroll
    for (int j = 0; j < 4; ++j) acc[i][j] = zero4;

  for (int k0 = 0; k0 < K; k0 += 32) {
    {
      const u16* gs[4] = {Ah, Al, Bh, Bl};
      const int r0s[4] = {row0, row0, col0, col0};
#pragma unroll
      for (int st = 0; st < 4; ++st) {
        u16* s = lds + st * 4096;
#pragma unroll
        for (int h = 0; h < 2; ++h) {
          int ch = h * 256 + w * 64 + l;
          const u16* gp = gs[st] + (size_t)(r0s[st] + (ch >> 2)) * K + k0 + (ch & 3) * 8;
          u16* sp = s + (h * 256 + w * 64) * 8;
          __builtin_amdgcn_global_load_lds((const __attribute__((address_space(1))) void*)gp,
                                           (__attribute__((address_space(3))) void*)sp, 16, 0, 0);
        }
      }
    }
    __syncthreads();
    short8 ah[4], al[4];
#pragma unroll
    for (int i = 0; i < 4; ++i) {
      int r = wm + i * 16 + lrow;
      ah[i] = *(const short8*)&lds[0 * 4096 + r * 32 + lk];
      al[i] = *(const short8*)&lds[1 * 4096 + r * 32 + lk];
    }
#pragma unroll
    for (int j = 0; j < 4; ++j) {
      int r = wn + j * 16 + lrow;
      short8 bh = *(const short8*)&lds[2 * 4096 + r * 32 + lk];
      short8 bl = *(const short8*)&lds[3 * 4096 + r * 32 + lk];
#pragma unroll
      for (int i = 0; i < 4; ++i) {
        acc[i][j] = __builtin_amdgcn_mfma_f32_16x16x32_bf16(ah[i], bh, acc[i][j], 0, 0, 0);
        acc[i][j] = __builtin_amdgcn_mfma_f32_16x16x32_bf16(ah[i], bl, acc[i][j], 0, 0, 0);
        acc[i][j] = __builtin_amdgcn_mfma_f32_16x16x32_bf16(al[i], bh, acc[i][j], 0, 0, 0);
      }
    }
    __syncthreads();
  }
#pragma unroll
  for (int i = 0; i < 4; ++i)
#pragma unroll
    for (int r = 0; r < 4; ++r) {
      int m = row0 + wm + i * 16 + ((l >> 4) << 2) + r;
      size_t base = (size_t)m * N;
#pragma unroll
      for (int j = 0; j < 4; ++j) {
        int n = col0 + wn + j * 16 + (l & 15);
        Cout[base + n] = acc[i][j][r];
      }
    }
}

// ---------------- fp32 GEMMs (one-time: Gram, recon; proven r3) ----------------
#define BM 128
#define BN 128
#define BKK 16

__global__ __launch_bounds__(256) void k_gram_f32(const float* __restrict__ A,
                                                  const float* __restrict__ Bt,
                                                  float* __restrict__ C, int M, int N, int Kd) {
  __shared__ float As[BKK][BM + 4];
  __shared__ float Bs[BKK][BN + 4];
  int tx = threadIdx.x & 15, ty = threadIdx.x >> 4;
  int row0 = blockIdx.y * BM, col0 = blockIdx.x * BN;
  float acc[8][8] = {};
  for (int k0 = 0; k0 < Kd; k0 += BKK) {
#pragma unroll
    for (int i = 0; i < 2; ++i) {
      int f = threadIdx.x + 256 * i;
      int r = f >> 2, kk = (f & 3) << 2;
      float4 a = *(const float4*)&A[(size_t)(row0 + r) * Kd + k0 + kk];
      As[kk + 0][r] = a.x; As[kk + 1][r] = a.y; As[kk + 2][r] = a.z; As[kk + 3][r] = a.w;
      float4 b = *(const float4*)&Bt[(size_t)(col0 + r) * Kd + k0 + kk];
      Bs[kk + 0][r] = b.x; Bs[kk + 1][r] = b.y; Bs[kk + 2][r] = b.z; Bs[kk + 3][r] = b.w;
    }
    __syncthreads();
#pragma unroll
    for (int k = 0; k < BKK; ++k) {
      float a[8], b[8];
      *(float4*)&a[0] = *(const float4*)&As[k][ty * 8];
      *(float4*)&a[4] = *(const float4*)&As[k][ty * 8 + 4];
      *(float4*)&b[0] = *(const float4*)&Bs[k][tx * 8];
      *(float4*)&b[4] = *(const float4*)&Bs[k][tx * 8 + 4];
#pragma unroll
      for (int i = 0; i < 8; ++i)
#pragma unroll
        for (int j = 0; j < 8; ++j) acc[i][j] = fmaf(a[i], b[j], acc[i][j]);
    }
    __syncthreads();
  }
  int m0 = row0 + ty * 8, n0 = col0 + tx * 8;
#pragma unroll
  for (int i = 0; i < 8; ++i)
#pragma unroll
    for (int j4 = 0; j4 < 2; ++j4) {
      float4 c;
      c.x = acc[i][j4 * 4 + 0]; c.y = acc[i][j4 * 4 + 1];
      c.z = acc[i][j4 * 4 + 2]; c.w = acc[i][j4 * 4 + 3];
      *(float4*)&C[(size_t)(m0 + i) * N + n0 + j4 * 4] = c;
    }
}

__global__ __launch_bounds__(256) void k_recon_f32(const float* __restrict__ A,
                                                   const float* __restrict__ Bm,
                                                   float* __restrict__ C, int M, int N, int Kd) {
  __shared__ float As[BKK][BM + 4];
  __shared__ float Bs[BKK][BN + 4];
  int tx = threadIdx.x & 15, ty = threadIdx.x >> 4;
  int row0 = blockIdx.y * BM, col0 = blockIdx.x * BN;
  float acc[8][8] = {};
  for (int k0 = 0; k0 < Kd; k0 += BKK) {
#pragma unroll
    for (int i = 0; i < 2; ++i) {
      int f = threadIdx.x + 256 * i;
      int r = f >> 2, kk = (f & 3) << 2;
      float4 a = *(const float4*)&A[(size_t)(row0 + r) * Kd + k0 + kk];
      As[kk + 0][r] = a.x; As[kk + 1][r] = a.y; As[kk + 2][r] = a.z; As[kk + 3][r] = a.w;
      int kr = f >> 5, nc = (f & 31) << 2;
      *(float4*)&Bs[kr][nc] = *(const float4*)&Bm[(size_t)(k0 + kr) * N + col0 + nc];
    }
    __syncthreads();
#pragma unroll
    for (int k = 0; k < BKK; ++k) {
      float a[8], b[8];
      *(float4*)&a[0] = *(const float4*)&As[k][ty * 8];
      *(float4*)&a[4] = *(const float4*)&As[k][ty * 8 + 4];
      *(float4*)&b[0] = *(const float4*)&Bs[k][tx * 8];
      *(float4*)&b[4] = *(const float4*)&Bs[k][tx * 8 + 4];
#pragma unroll
      for (int i = 0; i < 8; ++i)
#pragma unroll
        for (int j = 0; j < 8; ++j) acc[i][j] = fmaf(a[i], b[j], acc[i][j]);
    }
    __syncthreads();
  }
  int m0 = row0 + ty * 8, n0 = col0 + tx * 8;
#pragma unroll
  for (int i = 0; i < 8; ++i)
#pragma unroll
    for (int j4 = 0; j4 < 2; ++j4) {
      float4 c;
      c.x = acc[i][j4 * 4 + 0]; c.y = acc[i][j4 * 4 + 1];
      c.z = acc[i][j4 * 4 + 2]; c.w = acc[i][j4 * 4 + 3];
      *(float4*)&C[(size_t)(m0 + i) * N + n0 + j4 * 4] = c;
    }
}

// ---------------- fused FISTA iteration (cooperative) ----------------
// acc = y @ G  over logical K' = 6144 (segments: yh*Gh | yl*Gh | yh*Gl),
// then grid.sync, then in-place FISTA update of (Alpha, Yh, Yl).
// 256x256 tile, BK=64, 8 waves (2Mx4N), double-buffered 128KB static LDS,
// counted vmcnt(8), raw barriers, XOR bank swizzle (slot ^= row&7).

// stage one 256x64 operand tile: 2048 chunks of 16B, 512 threads x 4 instr.
// LDS linear dest; global source pre-swizzled (involution) per rule #21.
__device__ __forceinline__ void stage_op(const u16* src, int r0, int q0,
                                         u16* ldsbase, int tid) {
#pragma unroll
  for (int i = 0; i < 4; ++i) {
    int c = i * 512 + tid;
    int r = c >> 3;
    int sp = (c & 7) ^ (r & 7);
    const u16* gp = src + ((size_t)(r0 + r) << 11) + (q0 + (sp << 3));
    u16* lp = ldsbase + ((i * 512 + (tid & 448)) << 3);  // wave-uniform base
    __builtin_amdgcn_global_load_lds((const __attribute__((address_space(1))) void*)gp,
                                     (__attribute__((address_space(3))) void*)lp, 16, 0, 0);
  }
}

__global__ __launch_bounds__(512, 2) void k_fista_fused(
    u16* Yh, u16* Yl,
    const u16* __restrict__ Gh, const u16* __restrict__ Gl,
    const float* __restrict__ Cx, float* Alpha,
    const float* __restrict__ stepbuf, float mu) {
  __shared__ u16 lds[65536];  // 128 KB static: [buf][A 16384 u16 | B 16384 u16]

  const int tid = threadIdx.x;
  const int w = tid >> 6, l = tid & 63;
  const int wm = w >> 2, wn = w & 3;       // 2 x 4 waves
  const int lr = l & 15, lg = l >> 4;
  const int row0 = blockIdx.y * 256, col0 = blockIdx.x * 256;

  f32x4 acc[8][4];
  f32x4 zero4 = {0.f, 0.f, 0.f, 0.f};
#pragma unroll
  for (int i = 0; i < 8; ++i)
#pragma unroll
    for (int j = 0; j < 4; ++j) acc[i][j] = zero4;

  // prologue: stage tiles 0 (buf0) and 1 (buf1); both in segment 0 (Yh/Gh)
  stage_op(Yh, row0, 0, lds, tid);
  stage_op(Gh, col0, 0, lds + 16384, tid);
  stage_op(Yh, row0, 64, lds + 32768, tid);
  stage_op(Gh, col0, 64, lds + 49152, tid);

#define FBODY(TT, B)                                                              \
  {                                                                               \
    asm volatile("s_waitcnt vmcnt(8)" ::: "memory");                              \
    __builtin_amdgcn_s_barrier();                                                 \
    __builtin_amdgcn_sched_barrier(0);                                            \
    const u16* baseA = lds + ((B) ? 32768 : 0);                                   \
    const u16* baseB = baseA + 16384;                                             \
    short8 bf[4][2];                                                              \
    _Pragma("unroll") for (int j = 0; j < 4; ++j) {                               \
      _Pragma("unroll") for (int ks = 0; ks < 2; ++ks) {                          \
        int brow = wn * 64 + j * 16 + lr;                                         \
        int slot = ks * 4 + lg;                                                   \
        bf[j][ks] = *(const short8*)(baseB + brow * 64 + ((slot ^ (brow & 7)) << 3)); \
      }                                                                           \
    }                                                                             \
    _Pragma("unroll") for (int i = 0; i < 8; ++i) {                               \
      int arow = wm * 128 + i * 16 + lr;                                          \
      short8 a0 = *(const short8*)(baseA + arow * 64 + (((0 + lg) ^ (arow & 7)) << 3)); \
      short8 a1 = *(const short8*)(baseA + arow * 64 + (((4 + lg) ^ (arow & 7)) << 3)); \
      _Pragma("unroll") for (int j = 0; j < 4; ++j) {                             \
        acc[i][j] = __builtin_amdgcn_mfma_f32_16x16x32_bf16(a0, bf[j][0], acc[i][j], 0, 0, 0); \
        acc[i][j] = __builtin_amdgcn_mfma_f32_16x16x32_bf16(a1, bf[j][1], acc[i][j], 0, 0, 0); \
      }                                                                           \
    }                                                                             \
    __builtin_amdgcn_sched_barrier(0);                                            \
    __builtin_amdgcn_s_barrier();                                                 \
    __builtin_amdgcn_sched_barrier(0);                                            \
    int tn = (TT) + 2;                                                            \
    if (tn >= NTILES) tn -= NTILES;                                               \
    int k0n = tn << 6;                                                            \
    int sg = k0n >> 11;                                                           \
    int q0 = k0n & 2047;                                                          \
    stage_op(sg == 1 ? Yl : Yh, row0, q0, lds + ((B) ? 32768 : 0), tid);          \
    stage_op(sg == 2 ? Gl : Gh, col0, q0, lds + ((B) ? 32768 : 0) + 16384, tid);  \
  }

  for (int tt = 0; tt < NTILES; tt += 2) {
    FBODY(tt, 0)
    FBODY(tt + 1, 1)
  }
#undef FBODY

  asm volatile("s_waitcnt vmcnt(0)" ::: "memory");
  cg::this_grid().sync();

  // ---- fused FISTA epilogue: each block updates only its own C-tile ----
  const float step = stepbuf[0];
  const float thr = LAM * step;
#pragma unroll
  for (int i = 0; i < 8; ++i) {
#pragma unroll
    for (int r = 0; r < 4; ++r) {
      int m = row0 + wm * 128 + i * 16 + (lg << 2) + r;
      size_t base = (size_t)m * KB;
#pragma unroll
      for (int j = 0; j < 4; ++j) {
        int n = col0 + wn * 64 + j * 16 + lr;
        size_t idx = base + n;
        float g = acc[i][j][r] - Cx[idx];
        float y = bf2f(Yh[idx]) + bf2f(Yl[idx]);
        float z = y - step * g;
        float az = fabsf(z) - thr;
        float a = az > 0.f ? copysignf(az, z) : 0.f;
        float ap = Alpha[idx];
        float yn = a + mu * (a - ap);
        Alpha[idx] = a;
        u16 hh = f2bf(yn);
        Yh[idx] = hh;
        Yl[idx] = f2bf(yn - bf2f(hh));
      }
    }
  }
}

// ---------------- launch ----------------
extern "C" void kernel_launch(void* const* d_in, const int* in_sizes, int n_in,
                              void* d_out, int out_size, void* d_ws, size_t ws_size,
                              hipStream_t stream) {
  const float* x = (const float*)d_in[0];    // [8192,1024]
  const float* phi = (const float*)d_in[1];  // [2048,1024]
  float* out = (float*)d_out;
  float* alpha = out;                             // [8192*2048] fp32, in-place FISTA state
  float* reconF = out + (size_t)BATCH * KB;       // [8192*1024] fp32 (33.55 MB scratch region)

  // ---- workspace layout (byte offsets) ----
  char* ws = (char*)d_ws;
  u16* Yh = (u16*)ws;                                   // 33,554,432 B
  u16* Yl = (u16*)(ws + 33554432ull);                   // 33,554,432 B
  u16* Gph = (u16*)(ws + 67108864ull);                  // 8,388,608 B  (G' hi; temp phiH)
  u16* Gpl = (u16*)(ws + 75497472ull);                  // 8,388,608 B  (G' lo; temp phiL)
  float* Cx = (float*)(ws + 83886080ull);               // 67,108,864 B
  float* stepbuf = (float*)(ws + 150994944ull);         // 64 B
  const size_t need = 150995008ull;
  if (ws_size < need) return;

  // pre-FISTA temporaries:
  float* Gf = (float*)Yh;           // G fp32 [2048][2048] = 16.78 MB in Yh/Yl region
  u16* xh = (u16*)reconF;           // x split hi [8192*1024]
  u16* xl = xh + (size_t)BATCH * DD;
  float* vbuf = reconF;             // power-iter scratch (after Cx done, xh/xl dead)
  float* wbuf = reconF + 2048;
  float* normPart = reconF + 4096;  // 50*64
  float* LPart = reconF + 7296;     // 64

  // 1. splits: phi -> (Gph,Gpl temp), x -> (xh,xl in recon region)
  k_split_f32<<<2048, 256, 0, stream>>>(phi, Gph, Gpl, KB * DD);
  k_split_f32<<<2048, 256, 0, stream>>>(x, xh, xl, BATCH * DD);

  // 2. Cx = x @ phi^T (fp32 out), M=8192 N=2048 K=1024
  k_xphiT<<<dim3(KB / 128, BATCH / 128), 256, 0, stream>>>(xh, xl, Gph, Gpl, Cx, KB, DD);

  // 3. G = phi @ phi^T (fp32) into Yh region
  k_gram_f32<<<dim3(KB / BN, KB / BM), 256, 0, stream>>>(phi, phi, Gf, KB, KB, DD);

  // 4. power iteration -> step = 1/L  (scratch in recon region; xh/xl dead)
  k_init_v<<<8, 256, 0, stream>>>(vbuf);
  for (int s = 0; s < N_POWER; ++s) {
    k_power_matvec<0><<<64, 256, 0, stream>>>(Gf, vbuf, wbuf, normPart + s * 64);
    k_power_scale<<<KB / 256, 256, 0, stream>>>(wbuf, vbuf, normPart + s * 64);
  }
  k_power_matvec<1><<<64, 256, 0, stream>>>(Gf, vbuf, wbuf, LPart);
  k_compute_step<<<1, 1, 0, stream>>>(LPart, stepbuf);

  // 5. G' = split(G) (overwrites phi splits; they are dead)
  k_split_f32<<<2048, 256, 0, stream>>>(Gf, Gph, Gpl, KB * KB);

  // 6. zero Y (kills G) and alpha
  k_zero2<<<2048, 256, 0, stream>>>((float4*)Yh, (int)(67108864 / 16),
                                    (float4*)alpha, (int)(67108864 / 16));

  // 7. FISTA: 100 cooperative fused iterations
  float t = 1.f;
  float mus[N_ITER];
  for (int it = 0; it < N_ITER; ++it) {
    float tn = 0.5f * (1.f + sqrtf(1.f + 4.f * t * t));
    mus[it] = (t - 1.f) / tn;
    t = tn;
  }
  u16 *pYh = Yh, *pYl = Yl;
  const u16 *pGh = Gph, *pGl = Gpl;
  const float* pCx = Cx;
  float* pAl = alpha;
  const float* pStep = stepbuf;
  for (int it = 0; it < N_ITER; ++it) {
    void* kargs[8] = {&pYh, &pYl, &pGh, &pGl, &pCx, &pAl, &pStep, &mus[it]};
    hipLaunchCooperativeKernel((const void*)k_fista_fused, dim3(KB / 256, BATCH / 256),
                               dim3(512), kargs, 0, stream);
  }

  // 8. recon = alpha @ phi (fp32; overwrites recon-region scratch)
  k_recon_f32<<<dim3(DD / BN, BATCH / BM), 256, 0, stream>>>(
      alpha, phi, reconF, BATCH, DD, KB);
}

// Round 7
// 28917.075 us; speedup vs baseline: 3.1951x; 1.0032x over previous
//
#include <hip/hip_runtime.h>
#include <hip/hip_cooperative_groups.h>
#include <math.h>

namespace cg = cooperative_groups;

#define BATCH 8192
#define KB 2048      // num basis (N of fused GEMM)
#define DD 1024      // dim basis
#define LAM 0.1f
#define N_ITER 100
#define N_POWER 50
#define NTILES 96    // K' = 6144 = 96 * 64

typedef unsigned short u16;
using short8 = __attribute__((ext_vector_type(8))) short;
using f32x4  = __attribute__((ext_vector_type(4))) float;

// ---------- bf16 split helpers (RNE) ----------
__device__ __forceinline__ u16 f2bf(float f) {
  unsigned int u = __builtin_bit_cast(unsigned int, f);
  u = u + 0x7FFFu + ((u >> 16) & 1u);
  return (u16)(u >> 16);
}
__device__ __forceinline__ float bf2f(u16 s) {
  unsigned int u = ((unsigned int)s) << 16;
  return __builtin_bit_cast(float, u);
}

// ---------------- utility kernels ----------------
__global__ void k_split_f32(const float* __restrict__ in, u16* __restrict__ h,
                            u16* __restrict__ lo, int n) {
  for (int i = blockIdx.x * blockDim.x + threadIdx.x; i < n; i += gridDim.x * blockDim.x) {
    float v = in[i];
    u16 hh = f2bf(v);
    h[i] = hh;
    lo[i] = f2bf(v - bf2f(hh));
  }
}

__global__ void k_zero2(float4* __restrict__ a, int na, float4* __restrict__ b, int nb) {
  float4 z = {0.f, 0.f, 0.f, 0.f};
  for (int i = blockIdx.x * blockDim.x + threadIdx.x; i < na; i += gridDim.x * blockDim.x)
    a[i] = z;
  for (int i = blockIdx.x * blockDim.x + threadIdx.x; i < nb; i += gridDim.x * blockDim.x)
    b[i] = z;
}

__global__ void k_init_v(float* __restrict__ v) {
  int i = blockIdx.x * blockDim.x + threadIdx.x;
  if (i < KB) v[i] = 1.f;
}

// ---------------- power iteration (proven r3) ----------------
template <int MODE>
__global__ __launch_bounds__(256) void k_power_matvec(const float* __restrict__ G,
                                                      const float* __restrict__ vin,
                                                      float* __restrict__ wout,
                                                      float* __restrict__ partial) {
  int rloc = threadIdx.x >> 3;
  int seg = threadIdx.x & 7;
  int row = blockIdx.x * 32 + rloc;
  const float* g = G + (size_t)row * KB + seg * 256;
  const float* vv = vin + seg * 256;
  float s = 0.f;
#pragma unroll 8
  for (int j = 0; j < 256; j += 4) {
    float4 gg = *(const float4*)(g + j);
    float4 vx = *(const float4*)(vv + j);
    s = fmaf(gg.x, vx.x, fmaf(gg.y, vx.y, fmaf(gg.z, vx.z, fmaf(gg.w, vx.w, s))));
  }
#pragma unroll
  for (int off = 1; off < 8; off <<= 1) s += __shfl_xor(s, off, 64);
  if (seg == 0) wout[row] = s;
  float val = (seg == 0) ? (MODE ? vin[row] * s : s * s) : 0.f;
#pragma unroll
  for (int off = 8; off < 64; off <<= 1) val += __shfl_xor(val, off, 64);
  __shared__ float red[4];
  int lane = threadIdx.x & 63, wid = threadIdx.x >> 6;
  if (lane == 0) red[wid] = val;
  __syncthreads();
  if (threadIdx.x == 0) partial[blockIdx.x] = red[0] + red[1] + red[2] + red[3];
}

__global__ void k_power_scale(const float* __restrict__ w, float* __restrict__ v,
                              const float* __restrict__ partial) {
  float n2 = 0.f;
#pragma unroll
  for (int i = 0; i < 64; ++i) n2 += partial[i];
  int i = blockIdx.x * 256 + threadIdx.x;
  v[i] = w[i] / sqrtf(n2);
}

__global__ void k_compute_step(const float* __restrict__ partialL, float* __restrict__ stepbuf) {
  float L = 0.f;
#pragma unroll
  for (int i = 0; i < 64; ++i) L += partialL[i];
  stepbuf[0] = 1.f / L;
}

// ---------------- Cx = x @ phi^T (split-bf16 MFMA, fp32 out; r3-proven structure) ----------------
__global__ __launch_bounds__(256) void k_xphiT(
    const u16* __restrict__ Ah, const u16* __restrict__ Al,
    const u16* __restrict__ Bh, const u16* __restrict__ Bl,
    float* __restrict__ Cout, int N, int K) {
  __shared__ u16 lds[4 * 128 * 32];
  const int tid = threadIdx.x;
  const int w = tid >> 6, l = tid & 63;
  const int row0 = blockIdx.y * 128, col0 = blockIdx.x * 128;
  const int wm = (w >> 1) * 64, wn = (w & 1) * 64;
  const int lrow = l & 15, lk = (l >> 4) * 8;

  f32x4 zero4 = {0.f, 0.f, 0.f, 0.f};
  f32x4 acc[4][4];
#pragma unroll
  for (int i = 0; i < 4; ++i)
#pragma unroll
    for (int j = 0; j < 4; ++j) acc[i][j] = zero4;

  for (int k0 = 0; k0 < K; k0 += 32) {
    {
      const u16* gs[4] = {Ah, Al, Bh, Bl};
      const int r0s[4] = {row0, row0, col0, col0};
#pragma unroll
      for (int st = 0; st < 4; ++st) {
        u16* s = lds + st * 4096;
#pragma unroll
        for (int h = 0; h < 2; ++h) {
          int ch = h * 256 + w * 64 + l;
          const u16* gp = gs[st] + (size_t)(r0s[st] + (ch >> 2)) * K + k0 + (ch & 3) * 8;
          u16* sp = s + (h * 256 + w * 64) * 8;
          __builtin_amdgcn_global_load_lds((const __attribute__((address_space(1))) void*)gp,
                                           (__attribute__((address_space(3))) void*)sp, 16, 0, 0);
        }
      }
    }
    __syncthreads();
    short8 ah[4], al[4];
#pragma unroll
    for (int i = 0; i < 4; ++i) {
      int r = wm + i * 16 + lrow;
      ah[i] = *(const short8*)&lds[0 * 4096 + r * 32 + lk];
      al[i] = *(const short8*)&lds[1 * 4096 + r * 32 + lk];
    }
#pragma unroll
    for (int j = 0; j < 4; ++j) {
      int r = wn + j * 16 + lrow;
      short8 bh = *(const short8*)&lds[2 * 4096 + r * 32 + lk];
      short8 bl = *(const short8*)&lds[3 * 4096 + r * 32 + lk];
#pragma unroll
      for (int i = 0; i < 4; ++i) {
        acc[i][j] = __builtin_amdgcn_mfma_f32_16x16x32_bf16(ah[i], bh, acc[i][j], 0, 0, 0);
        acc[i][j] = __builtin_amdgcn_mfma_f32_16x16x32_bf16(ah[i], bl, acc[i][j], 0, 0, 0);
        acc[i][j] = __builtin_amdgcn_mfma_f32_16x16x32_bf16(al[i], bh, acc[i][j], 0, 0, 0);
      }
    }
    __syncthreads();
  }
#pragma unroll
  for (int i = 0; i < 4; ++i)
#pragma unroll
    for (int r = 0; r < 4; ++r) {
      int m = row0 + wm + i * 16 + ((l >> 4) << 2) + r;
      size_t base = (size_t)m * N;
#pragma unroll
      for (int j = 0; j < 4; ++j) {
        int n = col0 + wn + j * 16 + (l & 15);
        Cout[base + n] = acc[i][j][r];
      }
    }
}

// ---------------- fp32 GEMMs (one-time: Gram, recon; proven r3) ----------------
#define BM 128
#define BN 128
#define BKK 16

__global__ __launch_bounds__(256) void k_gram_f32(const float* __restrict__ A,
                                                  const float* __restrict__ Bt,
                                                  float* __restrict__ C, int M, int N, int Kd) {
  __shared__ float As[BKK][BM + 4];
  __shared__ float Bs[BKK][BN + 4];
  int tx = threadIdx.x & 15, ty = threadIdx.x >> 4;
  int row0 = blockIdx.y * BM, col0 = blockIdx.x * BN;
  float acc[8][8] = {};
  for (int k0 = 0; k0 < Kd; k0 += BKK) {
#pragma unroll
    for (int i = 0; i < 2; ++i) {
      int f = threadIdx.x + 256 * i;
      int r = f >> 2, kk = (f & 3) << 2;
      float4 a = *(const float4*)&A[(size_t)(row0 + r) * Kd + k0 + kk];
      As[kk + 0][r] = a.x; As[kk + 1][r] = a.y; As[kk + 2][r] = a.z; As[kk + 3][r] = a.w;
      float4 b = *(const float4*)&Bt[(size_t)(col0 + r) * Kd + k0 + kk];
      Bs[kk + 0][r] = b.x; Bs[kk + 1][r] = b.y; Bs[kk + 2][r] = b.z; Bs[kk + 3][r] = b.w;
    }
    __syncthreads();
#pragma unroll
    for (int k = 0; k < BKK; ++k) {
      float a[8], b[8];
      *(float4*)&a[0] = *(const float4*)&As[k][ty * 8];
      *(float4*)&a[4] = *(const float4*)&As[k][ty * 8 + 4];
      *(float4*)&b[0] = *(const float4*)&Bs[k][tx * 8];
      *(float4*)&b[4] = *(const float4*)&Bs[k][tx * 8 + 4];
#pragma unroll
      for (int i = 0; i < 8; ++i)
#pragma unroll
        for (int j = 0; j < 8; ++j) acc[i][j] = fmaf(a[i], b[j], acc[i][j]);
    }
    __syncthreads();
  }
  int m0 = row0 + ty * 8, n0 = col0 + tx * 8;
#pragma unroll
  for (int i = 0; i < 8; ++i)
#pragma unroll
    for (int j4 = 0; j4 < 2; ++j4) {
      float4 c;
      c.x = acc[i][j4 * 4 + 0]; c.y = acc[i][j4 * 4 + 1];
      c.z = acc[i][j4 * 4 + 2]; c.w = acc[i][j4 * 4 + 3];
      *(float4*)&C[(size_t)(m0 + i) * N + n0 + j4 * 4] = c;
    }
}

__global__ __launch_bounds__(256) void k_recon_f32(const float* __restrict__ A,
                                                   const float* __restrict__ Bm,
                                                   float* __restrict__ C, int M, int N, int Kd) {
  __shared__ float As[BKK][BM + 4];
  __shared__ float Bs[BKK][BN + 4];
  int tx = threadIdx.x & 15, ty = threadIdx.x >> 4;
  int row0 = blockIdx.y * BM, col0 = blockIdx.x * BN;
  float acc[8][8] = {};
  for (int k0 = 0; k0 < Kd; k0 += BKK) {
#pragma unroll
    for (int i = 0; i < 2; ++i) {
      int f = threadIdx.x + 256 * i;
      int r = f >> 2, kk = (f & 3) << 2;
      float4 a = *(const float4*)&A[(size_t)(row0 + r) * Kd + k0 + kk];
      As[kk + 0][r] = a.x; As[kk + 1][r] = a.y; As[kk + 2][r] = a.z; As[kk + 3][r] = a.w;
      int kr = f >> 5, nc = (f & 31) << 2;
      *(float4*)&Bs[kr][nc] = *(const float4*)&Bm[(size_t)(k0 + kr) * N + col0 + nc];
    }
    __syncthreads();
#pragma unroll
    for (int k = 0; k < BKK; ++k) {
      float a[8], b[8];
      *(float4*)&a[0] = *(const float4*)&As[k][ty * 8];
      *(float4*)&a[4] = *(const float4*)&As[k][ty * 8 + 4];
      *(float4*)&b[0] = *(const float4*)&Bs[k][tx * 8];
      *(float4*)&b[4] = *(const float4*)&Bs[k][tx * 8 + 4];
#pragma unroll
      for (int i = 0; i < 8; ++i)
#pragma unroll
        for (int j = 0; j < 8; ++j) acc[i][j] = fmaf(a[i], b[j], acc[i][j]);
    }
    __syncthreads();
  }
  int m0 = row0 + ty * 8, n0 = col0 + tx * 8;
#pragma unroll
  for (int i = 0; i < 8; ++i)
#pragma unroll
    for (int j4 = 0; j4 < 2; ++j4) {
      float4 c;
      c.x = acc[i][j4 * 4 + 0]; c.y = acc[i][j4 * 4 + 1];
      c.z = acc[i][j4 * 4 + 2]; c.w = acc[i][j4 * 4 + 3];
      *(float4*)&C[(size_t)(m0 + i) * N + n0 + j4 * 4] = c;
    }
}

// ---------------- fused FISTA iteration (cooperative) ----------------
// acc = y @ G  over logical K' = 6144 (segments: yh*Gh | yl*Gh | yh*Gl),
// then grid.sync, then in-place FISTA update of (Alpha, Yh, Yl).
// 256x256 tile, BK=64, 8 waves (2Mx4N), double-buffered 128KB static LDS,
// counted vmcnt(8), raw barriers, XOR bank swizzle (slot ^= row&7).
//
// __launch_bounds__(512, 1): 128KB LDS caps HW at 1 block/CU anyway; the
// former ",2" forced a 128-VGPR budget and spilled the 128-VGPR accumulator
// to scratch (r5 counters: VGPR_Count=124 < 128 acc regs, FETCH 595MB vs
// ~180MB ideal, MfmaUtil 12%). ",1" gives the 256-VGPR budget.

__device__ __forceinline__ void stage_op(const u16* src, int r0, int q0,
                                         u16* ldsbase, int tid) {
#pragma unroll
  for (int i = 0; i < 4; ++i) {
    int c = i * 512 + tid;
    int r = c >> 3;
    int sp = (c & 7) ^ (r & 7);
    const u16* gp = src + ((size_t)(r0 + r) << 11) + (q0 + (sp << 3));
    u16* lp = ldsbase + ((i * 512 + (tid & 448)) << 3);  // wave-uniform base
    __builtin_amdgcn_global_load_lds((const __attribute__((address_space(1))) void*)gp,
                                     (__attribute__((address_space(3))) void*)lp, 16, 0, 0);
  }
}

__global__ __launch_bounds__(512, 1) void k_fista_fused(
    u16* Yh, u16* Yl,
    const u16* __restrict__ Gh, const u16* __restrict__ Gl,
    const float* __restrict__ Cx, float* Alpha,
    const float* __restrict__ stepbuf, float mu) {
  __shared__ u16 lds[65536];  // 128 KB static: [buf][A 16384 u16 | B 16384 u16]

  const int tid = threadIdx.x;
  const int w = tid >> 6, l = tid & 63;
  const int wm = w >> 2, wn = w & 3;       // 2 x 4 waves
  const int lr = l & 15, lg = l >> 4;
  const int row0 = blockIdx.y * 256, col0 = blockIdx.x * 256;

  f32x4 acc[8][4];
  f32x4 zero4 = {0.f, 0.f, 0.f, 0.f};
#pragma unroll
  for (int i = 0; i < 8; ++i)
#pragma unroll
    for (int j = 0; j < 4; ++j) acc[i][j] = zero4;

  // prologue: stage tiles 0 (buf0) and 1 (buf1); both in segment 0 (Yh/Gh)
  stage_op(Yh, row0, 0, lds, tid);
  stage_op(Gh, col0, 0, lds + 16384, tid);
  stage_op(Yh, row0, 64, lds + 32768, tid);
  stage_op(Gh, col0, 64, lds + 49152, tid);

#define FBODY(TT, B)                                                              \
  {                                                                               \
    asm volatile("s_waitcnt vmcnt(8)" ::: "memory");                              \
    __builtin_amdgcn_s_barrier();                                                 \
    __builtin_amdgcn_sched_barrier(0);                                            \
    const u16* baseA = lds + ((B) ? 32768 : 0);                                   \
    const u16* baseB = baseA + 16384;                                             \
    short8 bf[4][2];                                                              \
    _Pragma("unroll") for (int j = 0; j < 4; ++j) {                               \
      _Pragma("unroll") for (int ks = 0; ks < 2; ++ks) {                          \
        int brow = wn * 64 + j * 16 + lr;                                         \
        int slot = ks * 4 + lg;                                                   \
        bf[j][ks] = *(const short8*)(baseB + brow * 64 + ((slot ^ (brow & 7)) << 3)); \
      }                                                                           \
    }                                                                             \
    _Pragma("unroll") for (int i = 0; i < 8; ++i) {                               \
      int arow = wm * 128 + i * 16 + lr;                                          \
      short8 a0 = *(const short8*)(baseA + arow * 64 + (((0 + lg) ^ (arow & 7)) << 3)); \
      short8 a1 = *(const short8*)(baseA + arow * 64 + (((4 + lg) ^ (arow & 7)) << 3)); \
      _Pragma("unroll") for (int j = 0; j < 4; ++j) {                             \
        acc[i][j] = __builtin_amdgcn_mfma_f32_16x16x32_bf16(a0, bf[j][0], acc[i][j], 0, 0, 0); \
        acc[i][j] = __builtin_amdgcn_mfma_f32_16x16x32_bf16(a1, bf[j][1], acc[i][j], 0, 0, 0); \
      }                                                                           \
    }                                                                             \
    __builtin_amdgcn_sched_barrier(0);                                            \
    __builtin_amdgcn_s_barrier();                                                 \
    __builtin_amdgcn_sched_barrier(0);                                            \
    int tn = (TT) + 2;                                                            \
    if (tn >= NTILES) tn -= NTILES;                                               \
    int k0n = tn << 6;                                                            \
    int sg = k0n >> 11;                                                           \
    int q0 = k0n & 2047;                                                          \
    stage_op(sg == 1 ? Yl : Yh, row0, q0, lds + ((B) ? 32768 : 0), tid);          \
    stage_op(sg == 2 ? Gl : Gh, col0, q0, lds + ((B) ? 32768 : 0) + 16384, tid);  \
  }

  for (int tt = 0; tt < NTILES; tt += 2) {
    FBODY(tt, 0)
    FBODY(tt + 1, 1)
  }
#undef FBODY

  asm volatile("s_waitcnt vmcnt(0)" ::: "memory");
  cg::this_grid().sync();

  // ---- fused FISTA epilogue: each block updates only its own C-tile ----
  const float step = stepbuf[0];
  const float thr = LAM * step;
#pragma unroll
  for (int i = 0; i < 8; ++i) {
#pragma unroll
    for (int r = 0; r < 4; ++r) {
      int m = row0 + wm * 128 + i * 16 + (lg << 2) + r;
      size_t base = (size_t)m * KB;
#pragma unroll
      for (int j = 0; j < 4; ++j) {
        int n = col0 + wn * 64 + j * 16 + lr;
        size_t idx = base + n;
        float g = acc[i][j][r] - Cx[idx];
        float y = bf2f(Yh[idx]) + bf2f(Yl[idx]);
        float z = y - step * g;
        float az = fabsf(z) - thr;
        float a = az > 0.f ? copysignf(az, z) : 0.f;
        float ap = Alpha[idx];
        float yn = a + mu * (a - ap);
        Alpha[idx] = a;
        u16 hh = f2bf(yn);
        Yh[idx] = hh;
        Yl[idx] = f2bf(yn - bf2f(hh));
      }
    }
  }
}

// ---------------- launch ----------------
extern "C" void kernel_launch(void* const* d_in, const int* in_sizes, int n_in,
                              void* d_out, int out_size, void* d_ws, size_t ws_size,
                              hipStream_t stream) {
  const float* x = (const float*)d_in[0];    // [8192,1024]
  const float* phi = (const float*)d_in[1];  // [2048,1024]
  float* out = (float*)d_out;
  float* alpha = out;                             // [8192*2048] fp32, in-place FISTA state
  float* reconF = out + (size_t)BATCH * KB;       // [8192*1024] fp32 (33.55 MB scratch region)

  // ---- workspace layout (byte offsets) ----
  char* ws = (char*)d_ws;
  u16* Yh = (u16*)ws;                                   // 33,554,432 B
  u16* Yl = (u16*)(ws + 33554432ull);                   // 33,554,432 B
  u16* Gph = (u16*)(ws + 67108864ull);                  // 8,388,608 B  (G' hi; temp phiH)
  u16* Gpl = (u16*)(ws + 75497472ull);                  // 8,388,608 B  (G' lo; temp phiL)
  float* Cx = (float*)(ws + 83886080ull);               // 67,108,864 B
  float* stepbuf = (float*)(ws + 150994944ull);         // 64 B
  const size_t need = 150995008ull;
  if (ws_size < need) return;

  // pre-FISTA temporaries:
  float* Gf = (float*)Yh;           // G fp32 [2048][2048] = 16.78 MB in Yh/Yl region
  u16* xh = (u16*)reconF;           // x split hi [8192*1024]
  u16* xl = xh + (size_t)BATCH * DD;
  float* vbuf = reconF;             // power-iter scratch (after Cx done, xh/xl dead)
  float* wbuf = reconF + 2048;
  float* normPart = reconF + 4096;  // 50*64
  float* LPart = reconF + 7296;     // 64

  // 1. splits: phi -> (Gph,Gpl temp), x -> (xh,xl in recon region)
  k_split_f32<<<2048, 256, 0, stream>>>(phi, Gph, Gpl, KB * DD);
  k_split_f32<<<2048, 256, 0, stream>>>(x, xh, xl, BATCH * DD);

  // 2. Cx = x @ phi^T (fp32 out), M=8192 N=2048 K=1024
  k_xphiT<<<dim3(KB / 128, BATCH / 128), 256, 0, stream>>>(xh, xl, Gph, Gpl, Cx, KB, DD);

  // 3. G = phi @ phi^T (fp32) into Yh region
  k_gram_f32<<<dim3(KB / BN, KB / BM), 256, 0, stream>>>(phi, phi, Gf, KB, KB, DD);

  // 4. power iteration -> step = 1/L  (scratch in recon region; xh/xl dead)
  k_init_v<<<8, 256, 0, stream>>>(vbuf);
  for (int s = 0; s < N_POWER; ++s) {
    k_power_matvec<0><<<64, 256, 0, stream>>>(Gf, vbuf, wbuf, normPart + s * 64);
    k_power_scale<<<KB / 256, 256, 0, stream>>>(wbuf, vbuf, normPart + s * 64);
  }
  k_power_matvec<1><<<64, 256, 0, stream>>>(Gf, vbuf, wbuf, LPart);
  k_compute_step<<<1, 1, 0, stream>>>(LPart, stepbuf);

  // 5. G' = split(G) (overwrites phi splits; they are dead)
  k_split_f32<<<2048, 256, 0, stream>>>(Gf, Gph, Gpl, KB * KB);

  // 6. zero Y (kills G) and alpha
  k_zero2<<<2048, 256, 0, stream>>>((float4*)Yh, (int)(67108864 / 16),
                                    (float4*)alpha, (int)(67108864 / 16));

  // 7. FISTA: 100 cooperative fused iterations
  float t = 1.f;
  float mus[N_ITER];
  for (int it = 0; it < N_ITER; ++it) {
    float tn = 0.5f * (1.f + sqrtf(1.f + 4.f * t * t));
    mus[it] = (t - 1.f) / tn;
    t = tn;
  }
  u16 *pYh = Yh, *pYl = Yl;
  const u16 *pGh = Gph, *pGl = Gpl;
  const float* pCx = Cx;
  float* pAl = alpha;
  const float* pStep = stepbuf;
  for (int it = 0; it < N_ITER; ++it) {
    void* kargs[8] = {&pYh, &pYl, &pGh, &pGl, &pCx, &pAl, &pStep, &mus[it]};
    hipLaunchCooperativeKernel((const void*)k_fista_fused, dim3(KB / 256, BATCH / 256),
                               dim3(512), kargs, 0, stream);
  }

  // 8. recon = alpha @ phi (fp32; overwrites recon-region scratch)
  k_recon_f32<<<dim3(DD / BN, BATCH / BM), 256, 0, stream>>>(
      alpha, phi, reconF, BATCH, DD, KB);
}

// Round 9
// 28057.422 us; speedup vs baseline: 3.2930x; 1.0306x over previous
//
#include <hip/hip_runtime.h>
#include <hip/hip_cooperative_groups.h>
#include <math.h>

namespace cg = cooperative_groups;

#define BATCH 8192
#define KB 2048      // num basis (N of fused GEMM)
#define DD 1024      // dim basis
#define LAM 0.1f
#define N_ITER 100
#define N_POWER 50
#define NTILES 96    // K' = 6144 = 96 * 64

typedef unsigned short u16;
using short8 = __attribute__((ext_vector_type(8))) short;
using f32x4  = __attribute__((ext_vector_type(4))) float;

// ---------- bf16 split helpers (RNE) ----------
__device__ __forceinline__ u16 f2bf(float f) {
  unsigned int u = __builtin_bit_cast(unsigned int, f);
  u = u + 0x7FFFu + ((u >> 16) & 1u);
  return (u16)(u >> 16);
}
__device__ __forceinline__ float bf2f(u16 s) {
  unsigned int u = ((unsigned int)s) << 16;
  return __builtin_bit_cast(float, u);
}

// ---------------- utility kernels ----------------
__global__ void k_split_f32(const float* __restrict__ in, u16* __restrict__ h,
                            u16* __restrict__ lo, int n) {
  for (int i = blockIdx.x * blockDim.x + threadIdx.x; i < n; i += gridDim.x * blockDim.x) {
    float v = in[i];
    u16 hh = f2bf(v);
    h[i] = hh;
    lo[i] = f2bf(v - bf2f(hh));
  }
}

__global__ void k_zero2(float4* __restrict__ a, int na, float4* __restrict__ b, int nb) {
  float4 z = {0.f, 0.f, 0.f, 0.f};
  for (int i = blockIdx.x * blockDim.x + threadIdx.x; i < na; i += gridDim.x * blockDim.x)
    a[i] = z;
  for (int i = blockIdx.x * blockDim.x + threadIdx.x; i < nb; i += gridDim.x * blockDim.x)
    b[i] = z;
}

__global__ void k_init_v(float* __restrict__ v) {
  int i = blockIdx.x * blockDim.x + threadIdx.x;
  if (i < KB) v[i] = 1.f;
}

// ---------------- power iteration (proven r3) ----------------
template <int MODE>
__global__ __launch_bounds__(256) void k_power_matvec(const float* __restrict__ G,
                                                      const float* __restrict__ vin,
                                                      float* __restrict__ wout,
                                                      float* __restrict__ partial) {
  int rloc = threadIdx.x >> 3;
  int seg = threadIdx.x & 7;
  int row = blockIdx.x * 32 + rloc;
  const float* g = G + (size_t)row * KB + seg * 256;
  const float* vv = vin + seg * 256;
  float s = 0.f;
#pragma unroll 8
  for (int j = 0; j < 256; j += 4) {
    float4 gg = *(const float4*)(g + j);
    float4 vx = *(const float4*)(vv + j);
    s = fmaf(gg.x, vx.x, fmaf(gg.y, vx.y, fmaf(gg.z, vx.z, fmaf(gg.w, vx.w, s))));
  }
#pragma unroll
  for (int off = 1; off < 8; off <<= 1) s += __shfl_xor(s, off, 64);
  if (seg == 0) wout[row] = s;
  float val = (seg == 0) ? (MODE ? vin[row] * s : s * s) : 0.f;
#pragma unroll
  for (int off = 8; off < 64; off <<= 1) val += __shfl_xor(val, off, 64);
  __shared__ float red[4];
  int lane = threadIdx.x & 63, wid = threadIdx.x >> 6;
  if (lane == 0) red[wid] = val;
  __syncthreads();
  if (threadIdx.x == 0) partial[blockIdx.x] = red[0] + red[1] + red[2] + red[3];
}

__global__ void k_power_scale(const float* __restrict__ w, float* __restrict__ v,
                              const float* __restrict__ partial) {
  float n2 = 0.f;
#pragma unroll
  for (int i = 0; i < 64; ++i) n2 += partial[i];
  int i = blockIdx.x * 256 + threadIdx.x;
  v[i] = w[i] / sqrtf(n2);
}

__global__ void k_compute_step(const float* __restrict__ partialL, float* __restrict__ stepbuf) {
  float L = 0.f;
#pragma unroll
  for (int i = 0; i < 64; ++i) L += partialL[i];
  stepbuf[0] = 1.f / L;
}

// ---------------- Cx = x @ phi^T (split-bf16 MFMA, fp32 out; r3-proven structure) ----------------
__global__ __launch_bounds__(256) void k_xphiT(
    const u16* __restrict__ Ah, const u16* __restrict__ Al,
    const u16* __restrict__ Bh, const u16* __restrict__ Bl,
    float* __restrict__ Cout, int N, int K) {
  __shared__ u16 lds[4 * 128 * 32];
  const int tid = threadIdx.x;
  const int w = tid >> 6, l = tid & 63;
  const int row0 = blockIdx.y * 128, col0 = blockIdx.x * 128;
  const int wm = (w >> 1) * 64, wn = (w & 1) * 64;
  const int lrow = l & 15, lk = (l >> 4) * 8;

  f32x4 zero4 = {0.f, 0.f, 0.f, 0.f};
  f32x4 acc[4][4];
#pragma unroll
  for (int i = 0; i < 4; ++i)
#pragma unroll
    for (int j = 0; j < 4; ++j) acc[i][j] = zero4;

  for (int k0 = 0; k0 < K; k0 += 32) {
    {
      const u16* gs[4] = {Ah, Al, Bh, Bl};
      const int r0s[4] = {row0, row0, col0, col0};
#pragma unroll
      for (int st = 0; st < 4; ++st) {
        u16* s = lds + st * 4096;
#pragma unroll
        for (int h = 0; h < 2; ++h) {
          int ch = h * 256 + w * 64 + l;
          const u16* gp = gs[st] + (size_t)(r0s[st] + (ch >> 2)) * K + k0 + (ch & 3) * 8;
          u16* sp = s + (h * 256 + w * 64) * 8;
          __builtin_amdgcn_global_load_lds((const __attribute__((address_space(1))) void*)gp,
                                           (__attribute__((address_space(3))) void*)sp, 16, 0, 0);
        }
      }
    }
    __syncthreads();
    short8 ah[4], al[4];
#pragma unroll
    for (int i = 0; i < 4; ++i) {
      int r = wm + i * 16 + lrow;
      ah[i] = *(const short8*)&lds[0 * 4096 + r * 32 + lk];
      al[i] = *(const short8*)&lds[1 * 4096 + r * 32 + lk];
    }
#pragma unroll
    for (int j = 0; j < 4; ++j) {
      int r = wn + j * 16 + lrow;
      short8 bh = *(const short8*)&lds[2 * 4096 + r * 32 + lk];
      short8 bl = *(const short8*)&lds[3 * 4096 + r * 32 + lk];
#pragma unroll
      for (int i = 0; i < 4; ++i) {
        acc[i][j] = __builtin_amdgcn_mfma_f32_16x16x32_bf16(ah[i], bh, acc[i][j], 0, 0, 0);
        acc[i][j] = __builtin_amdgcn_mfma_f32_16x16x32_bf16(ah[i], bl, acc[i][j], 0, 0, 0);
        acc[i][j] = __builtin_amdgcn_mfma_f32_16x16x32_bf16(al[i], bh, acc[i][j], 0, 0, 0);
      }
    }
    __syncthreads();
  }
#pragma unroll
  for (int i = 0; i < 4; ++i)
#pragma unroll
    for (int r = 0; r < 4; ++r) {
      int m = row0 + wm + i * 16 + ((l >> 4) << 2) + r;
      size_t base = (size_t)m * N;
#pragma unroll
      for (int j = 0; j < 4; ++j) {
        int n = col0 + wn + j * 16 + (l & 15);
        Cout[base + n] = acc[i][j][r];
      }
    }
}

// ---------------- fp32 GEMMs (one-time: Gram, recon; proven r3) ----------------
#define BM 128
#define BN 128
#define BKK 16

__global__ __launch_bounds__(256) void k_gram_f32(const float* __restrict__ A,
                                                  const float* __restrict__ Bt,
                                                  float* __restrict__ C, int M, int N, int Kd) {
  __shared__ float As[BKK][BM + 4];
  __shared__ float Bs[BKK][BN + 4];
  int tx = threadIdx.x & 15, ty = threadIdx.x >> 4;
  int row0 = blockIdx.y * BM, col0 = blockIdx.x * BN;
  float acc[8][8] = {};
  for (int k0 = 0; k0 < Kd; k0 += BKK) {
#pragma unroll
    for (int i = 0; i < 2; ++i) {
      int f = threadIdx.x + 256 * i;
      int r = f >> 2, kk = (f & 3) << 2;
      float4 a = *(const float4*)&A[(size_t)(row0 + r) * Kd + k0 + kk];
      As[kk + 0][r] = a.x; As[kk + 1][r] = a.y; As[kk + 2][r] = a.z; As[kk + 3][r] = a.w;
      float4 b = *(const float4*)&Bt[(size_t)(col0 + r) * Kd + k0 + kk];
      Bs[kk + 0][r] = b.x; Bs[kk + 1][r] = b.y; Bs[kk + 2][r] = b.z; Bs[kk + 3][r] = b.w;
    }
    __syncthreads();
#pragma unroll
    for (int k = 0; k < BKK; ++k) {
      float a[8], b[8];
      *(float4*)&a[0] = *(const float4*)&As[k][ty * 8];
      *(float4*)&a[4] = *(const float4*)&As[k][ty * 8 + 4];
      *(float4*)&b[0] = *(const float4*)&Bs[k][tx * 8];
      *(float4*)&b[4] = *(const float4*)&Bs[k][tx * 8 + 4];
#pragma unroll
      for (int i = 0; i < 8; ++i)
#pragma unroll
        for (int j = 0; j < 8; ++j) acc[i][j] = fmaf(a[i], b[j], acc[i][j]);
    }
    __syncthreads();
  }
  int m0 = row0 + ty * 8, n0 = col0 + tx * 8;
#pragma unroll
  for (int i = 0; i < 8; ++i)
#pragma unroll
    for (int j4 = 0; j4 < 2; ++j4) {
      float4 c;
      c.x = acc[i][j4 * 4 + 0]; c.y = acc[i][j4 * 4 + 1];
      c.z = acc[i][j4 * 4 + 2]; c.w = acc[i][j4 * 4 + 3];
      *(float4*)&C[(size_t)(m0 + i) * N + n0 + j4 * 4] = c;
    }
}

__global__ __launch_bounds__(256) void k_recon_f32(const float* __restrict__ A,
                                                   const float* __restrict__ Bm,
                                                   float* __restrict__ C, int M, int N, int Kd) {
  __shared__ float As[BKK][BM + 4];
  __shared__ float Bs[BKK][BN + 4];
  int tx = threadIdx.x & 15, ty = threadIdx.x >> 4;
  int row0 = blockIdx.y * BM, col0 = blockIdx.x * BN;
  float acc[8][8] = {};
  for (int k0 = 0; k0 < Kd; k0 += BKK) {
#pragma unroll
    for (int i = 0; i < 2; ++i) {
      int f = threadIdx.x + 256 * i;
      int r = f >> 2, kk = (f & 3) << 2;
      float4 a = *(const float4*)&A[(size_t)(row0 + r) * Kd + k0 + kk];
      As[kk + 0][r] = a.x; As[kk + 1][r] = a.y; As[kk + 2][r] = a.z; As[kk + 3][r] = a.w;
      int kr = f >> 5, nc = (f & 31) << 2;
      *(float4*)&Bs[kr][nc] = *(const float4*)&Bm[(size_t)(k0 + kr) * N + col0 + nc];
    }
    __syncthreads();
#pragma unroll
    for (int k = 0; k < BKK; ++k) {
      float a[8], b[8];
      *(float4*)&a[0] = *(const float4*)&As[k][ty * 8];
      *(float4*)&a[4] = *(const float4*)&As[k][ty * 8 + 4];
      *(float4*)&b[0] = *(const float4*)&Bs[k][tx * 8];
      *(float4*)&b[4] = *(const float4*)&Bs[k][tx * 8 + 4];
#pragma unroll
      for (int i = 0; i < 8; ++i)
#pragma unroll
        for (int j = 0; j < 8; ++j) acc[i][j] = fmaf(a[i], b[j], acc[i][j]);
    }
    __syncthreads();
  }
  int m0 = row0 + ty * 8, n0 = col0 + tx * 8;
#pragma unroll
  for (int i = 0; i < 8; ++i)
#pragma unroll
    for (int j4 = 0; j4 < 2; ++j4) {
      float4 c;
      c.x = acc[i][j4 * 4 + 0]; c.y = acc[i][j4 * 4 + 1];
      c.z = acc[i][j4 * 4 + 2]; c.w = acc[i][j4 * 4 + 3];
      *(float4*)&C[(size_t)(m0 + i) * N + n0 + j4 * 4] = c;
    }
}

// ---------------- fused FISTA iteration (cooperative) ----------------
// acc = y @ G  over logical K' = 6144 (segments: yh*Gh | yl*Gh | yh*Gl),
// then grid.sync, then in-place FISTA update of (Alpha, Yh, Yl).
// 256x256 tile, BK=64, 8 waves (2Mx4N), double-buffered 128KB static LDS,
// counted vmcnt(8), raw barriers, XOR bank swizzle (slot ^= row&7).
//
// r7 evidence: VGPR=124 both with (512,2) and (512,1), identical perf ->
// acc lives in AGPRs (unified file), never spilled. FETCH=595MB/iter is
// REAL traffic: 8 bx-blocks x 67MB Y-panel re-reads across different XCDs.
// This round: XCD-aware remap so same-by blocks share one XCD's L2 (T1),
// plus T5 setprio around the MFMA cluster.

__device__ __forceinline__ void stage_op(const u16* src, int r0, int q0,
                                         u16* ldsbase, int tid) {
#pragma unroll
  for (int i = 0; i < 4; ++i) {
    int c = i * 512 + tid;
    int r = c >> 3;
    int sp = (c & 7) ^ (r & 7);
    const u16* gp = src + ((size_t)(r0 + r) << 11) + (q0 + (sp << 3));
    u16* lp = ldsbase + ((i * 512 + (tid & 448)) << 3);  // wave-uniform base
    __builtin_amdgcn_global_load_lds((const __attribute__((address_space(1))) void*)gp,
                                     (__attribute__((address_space(3))) void*)lp, 16, 0, 0);
  }
}

__global__ __launch_bounds__(512, 1) void k_fista_fused(
    u16* Yh, u16* Yl,
    const u16* __restrict__ Gh, const u16* __restrict__ Gl,
    const float* __restrict__ Cx, float* Alpha,
    const float* __restrict__ stepbuf, float mu) {
  __shared__ u16 lds[65536];  // 128 KB static: [buf][A 16384 u16 | B 16384 u16]

  const int tid = threadIdx.x;
  const int w = tid >> 6, l = tid & 63;
  const int wm = w >> 2, wn = w & 3;       // 2 x 4 waves
  const int lr = l & 15, lg = l >> 4;

  // XCD-aware remap: lin%8 == by%8 so the 8 blocks sharing Y-panel `by`
  // land on one XCD (round-robin lin->XCD). Bijection on the 8x32 grid.
  const int lin = blockIdx.x + (int)gridDim.x * blockIdx.y;  // [0,256)
  const int bq = lin >> 6;          // [0,4)
  const int bp = (lin >> 3) & 7;    // [0,8)
  const int br = lin & 7;           // [0,8)
  const int row0 = ((bq << 3) + br) * 256;  // by = 8q + r
  const int col0 = bp * 256;                // bx = p

  f32x4 acc[8][4];
  f32x4 zero4 = {0.f, 0.f, 0.f, 0.f};
#pragma unroll
  for (int i = 0; i < 8; ++i)
#pragma unroll
    for (int j = 0; j < 4; ++j) acc[i][j] = zero4;

  // prologue: stage tiles 0 (buf0) and 1 (buf1); both in segment 0 (Yh/Gh)
  stage_op(Yh, row0, 0, lds, tid);
  stage_op(Gh, col0, 0, lds + 16384, tid);
  stage_op(Yh, row0, 64, lds + 32768, tid);
  stage_op(Gh, col0, 64, lds + 49152, tid);

#define FBODY(TT, B)                                                              \
  {                                                                               \
    asm volatile("s_waitcnt vmcnt(8)" ::: "memory");                              \
    __builtin_amdgcn_s_barrier();                                                 \
    __builtin_amdgcn_sched_barrier(0);                                            \
    const u16* baseA = lds + ((B) ? 32768 : 0);                                   \
    const u16* baseB = baseA + 16384;                                             \
    short8 bf[4][2];                                                              \
    _Pragma("unroll") for (int j = 0; j < 4; ++j) {                               \
      _Pragma("unroll") for (int ks = 0; ks < 2; ++ks) {                          \
        int brow = wn * 64 + j * 16 + lr;                                         \
        int slot = ks * 4 + lg;                                                   \
        bf[j][ks] = *(const short8*)(baseB + brow * 64 + ((slot ^ (brow & 7)) << 3)); \
      }                                                                           \
    }                                                                             \
    __builtin_amdgcn_s_setprio(1);                                                \
    _Pragma("unroll") for (int i = 0; i < 8; ++i) {                               \
      int arow = wm * 128 + i * 16 + lr;                                          \
      short8 a0 = *(const short8*)(baseA + arow * 64 + (((0 + lg) ^ (arow & 7)) << 3)); \
      short8 a1 = *(const short8*)(baseA + arow * 64 + (((4 + lg) ^ (arow & 7)) << 3)); \
      _Pragma("unroll") for (int j = 0; j < 4; ++j) {                             \
        acc[i][j] = __builtin_amdgcn_mfma_f32_16x16x32_bf16(a0, bf[j][0], acc[i][j], 0, 0, 0); \
        acc[i][j] = __builtin_amdgcn_mfma_f32_16x16x32_bf16(a1, bf[j][1], acc[i][j], 0, 0, 0); \
      }                                                                           \
    }                                                                             \
    __builtin_amdgcn_s_setprio(0);                                                \
    __builtin_amdgcn_sched_barrier(0);                                            \
    __builtin_amdgcn_s_barrier();                                                 \
    __builtin_amdgcn_sched_barrier(0);                                            \
    int tn = (TT) + 2;                                                            \
    if (tn >= NTILES) tn -= NTILES;                                               \
    int k0n = tn << 6;                                                            \
    int sg = k0n >> 11;                                                           \
    int q0 = k0n & 2047;                                                          \
    stage_op(sg == 1 ? Yl : Yh, row0, q0, lds + ((B) ? 32768 : 0), tid);          \
    stage_op(sg == 2 ? Gl : Gh, col0, q0, lds + ((B) ? 32768 : 0) + 16384, tid);  \
  }

  for (int tt = 0; tt < NTILES; tt += 2) {
    FBODY(tt, 0)
    FBODY(tt + 1, 1)
  }
#undef FBODY

  asm volatile("s_waitcnt vmcnt(0)" ::: "memory");
  cg::this_grid().sync();

  // ---- fused FISTA epilogue: each block updates only its own C-tile ----
  const float step = stepbuf[0];
  const float thr = LAM * step;
#pragma unroll
  for (int i = 0; i < 8; ++i) {
#pragma unroll
    for (int r = 0; r < 4; ++r) {
      int m = row0 + wm * 128 + i * 16 + (lg << 2) + r;
      size_t base = (size_t)m * KB;
#pragma unroll
      for (int j = 0; j < 4; ++j) {
        int n = col0 + wn * 64 + j * 16 + lr;
        size_t idx = base + n;
        float g = acc[i][j][r] - Cx[idx];
        float y = bf2f(Yh[idx]) + bf2f(Yl[idx]);
        float z = y - step * g;
        float az = fabsf(z) - thr;
        float a = az > 0.f ? copysignf(az, z) : 0.f;
        float ap = Alpha[idx];
        float yn = a + mu * (a - ap);
        Alpha[idx] = a;
        u16 hh = f2bf(yn);
        Yh[idx] = hh;
        Yl[idx] = f2bf(yn - bf2f(hh));
      }
    }
  }
}

// ---------------- launch ----------------
extern "C" void kernel_launch(void* const* d_in, const int* in_sizes, int n_in,
                              void* d_out, int out_size, void* d_ws, size_t ws_size,
                              hipStream_t stream) {
  const float* x = (const float*)d_in[0];    // [8192,1024]
  const float* phi = (const float*)d_in[1];  // [2048,1024]
  float* out = (float*)d_out;
  float* alpha = out;                             // [8192*2048] fp32, in-place FISTA state
  float* reconF = out + (size_t)BATCH * KB;       // [8192*1024] fp32 (33.55 MB scratch region)

  // ---- workspace layout (byte offsets) ----
  char* ws = (char*)d_ws;
  u16* Yh = (u16*)ws;                                   // 33,554,432 B
  u16* Yl = (u16*)(ws + 33554432ull);                   // 33,554,432 B
  u16* Gph = (u16*)(ws + 67108864ull);                  // 8,388,608 B  (G' hi; temp phiH)
  u16* Gpl = (u16*)(ws + 75497472ull);                  // 8,388,608 B  (G' lo; temp phiL)
  float* Cx = (float*)(ws + 83886080ull);               // 67,108,864 B
  float* stepbuf = (float*)(ws + 150994944ull);         // 64 B
  const size_t need = 150995008ull;
  if (ws_size < need) return;

  // pre-FISTA temporaries:
  float* Gf = (float*)Yh;           // G fp32 [2048][2048] = 16.78 MB in Yh/Yl region
  u16* xh = (u16*)reconF;           // x split hi [8192*1024]
  u16* xl = xh + (size_t)BATCH * DD;
  float* vbuf = reconF;             // power-iter scratch (after Cx done, xh/xl dead)
  float* wbuf = reconF + 2048;
  float* normPart = reconF + 4096;  // 50*64
  float* LPart = reconF + 7296;     // 64

  // 1. splits: phi -> (Gph,Gpl temp), x -> (xh,xl in recon region)
  k_split_f32<<<2048, 256, 0, stream>>>(phi, Gph, Gpl, KB * DD);
  k_split_f32<<<2048, 256, 0, stream>>>(x, xh, xl, BATCH * DD);

  // 2. Cx = x @ phi^T (fp32 out), M=8192 N=2048 K=1024
  k_xphiT<<<dim3(KB / 128, BATCH / 128), 256, 0, stream>>>(xh, xl, Gph, Gpl, Cx, KB, DD);

  // 3. G = phi @ phi^T (fp32) into Yh region
  k_gram_f32<<<dim3(KB / BN, KB / BM), 256, 0, stream>>>(phi, phi, Gf, KB, KB, DD);

  // 4. power iteration -> step = 1/L  (scratch in recon region; xh/xl dead)
  k_init_v<<<8, 256, 0, stream>>>(vbuf);
  for (int s = 0; s < N_POWER; ++s) {
    k_power_matvec<0><<<64, 256, 0, stream>>>(Gf, vbuf, wbuf, normPart + s * 64);
    k_power_scale<<<KB / 256, 256, 0, stream>>>(wbuf, vbuf, normPart + s * 64);
  }
  k_power_matvec<1><<<64, 256, 0, stream>>>(Gf, vbuf, wbuf, LPart);
  k_compute_step<<<1, 1, 0, stream>>>(LPart, stepbuf);

  // 5. G' = split(G) (overwrites phi splits; they are dead)
  k_split_f32<<<2048, 256, 0, stream>>>(Gf, Gph, Gpl, KB * KB);

  // 6. zero Y (kills G) and alpha
  k_zero2<<<2048, 256, 0, stream>>>((float4*)Yh, (int)(67108864 / 16),
                                    (float4*)alpha, (int)(67108864 / 16));

  // 7. FISTA: 100 cooperative fused iterations
  float t = 1.f;
  float mus[N_ITER];
  for (int it = 0; it < N_ITER; ++it) {
    float tn = 0.5f * (1.f + sqrtf(1.f + 4.f * t * t));
    mus[it] = (t - 1.f) / tn;
    t = tn;
  }
  u16 *pYh = Yh, *pYl = Yl;
  const u16 *pGh = Gph, *pGl = Gpl;
  const float* pCx = Cx;
  float* pAl = alpha;
  const float* pStep = stepbuf;
  for (int it = 0; it < N_ITER; ++it) {
    void* kargs[8] = {&pYh, &pYl, &pGh, &pGl, &pCx, &pAl, &pStep, &mus[it]};
    (void)hipLaunchCooperativeKernel((const void*)k_fista_fused, dim3(KB / 256, BATCH / 256),
                                     dim3(512), kargs, 0, stream);
  }

  // 8. recon = alpha @ phi (fp32; overwrites recon-region scratch)
  k_recon_f32<<<dim3(DD / BN, BATCH / BM), 256, 0, stream>>>(
      alpha, phi, reconF, BATCH, DD, KB);
}